// Round 10
// baseline (5358.803 us; speedup 1.0000x reference)
//
#include <hip/hip_runtime.h>
#include <hip/hip_bf16.h>

using bf16 = __hip_bfloat16;
using short8  = __attribute__((ext_vector_type(8))) short;
using floatx4 = __attribute__((ext_vector_type(4))) float;
using ull = unsigned long long;

constexpr int Bn = 4, Np = 1024, Gn = 128, Kn = 32;
constexpr int DM = 384, DEPTH = 12, CLSn = 40;
constexpr int DI = 768, DSt = 16, DTR = 24;
constexpr int Ln = 384;
constexpr int NCH = 12, CHS = 32;      // legacy scan (small path)
constexpr int CHB = 8,  NCB = 48;      // big-path scan: 8-step chunks
constexpr int XDBS = 1536*56;
constexpr int MC = 4096;               // encoder chunk rows (small path)
constexpr int MGRID = 256;             // mega kernel grid (1 block/CU worst case -> co-resident)
constexpr float EPSf = 1e-5f;
constexpr float BNS = 0.99999500003749968752f; // 1/sqrt(1+1e-5)
constexpr float LOG2E = 1.4426950408889634f;

static __device__ __forceinline__ short f2bf(float f){
  bf16 h = __float2bfloat16(f);
  return *reinterpret_cast<short*>(&h);
}
static __device__ __forceinline__ float fsig(float x){ return 1.f/(1.f + __expf(-x)); }
static __device__ __forceinline__ float fsoftplus(float x){
  return fmaxf(x, 0.f) + __logf(1.f + __expf(-fabsf(x)));
}
static __device__ __forceinline__ ull umax64(ull a, ull b){ return a > b ? a : b; }

template<int CTRL>
static __device__ __forceinline__ int dppmov(int x){
  return __builtin_amdgcn_update_dpp(0, x, CTRL, 0xF, 0xF, true);
}
static __device__ __forceinline__ ull redmax64(ull key){
  #define RSTEP(CTRL) { \
    int hi = (int)(unsigned)(key >> 32), lo = (int)(unsigned)key; \
    int h2 = dppmov<CTRL>(hi), l2 = dppmov<CTRL>(lo); \
    ull k2 = ((ull)(unsigned)h2 << 32) | (unsigned)l2; \
    if (k2 > key) key = k2; }
  RSTEP(0x111) RSTEP(0x112) RSTEP(0x114) RSTEP(0x118) RSTEP(0x142) RSTEP(0x143)
  #undef RSTEP
  return key;
}

// ---------------- device-scope generational grid barrier (all blocks co-resident)
static __device__ __forceinline__ void gbar(int* cnt, int* gen){
  __syncthreads();
  if (threadIdx.x == 0){
    __threadfence();
    int g = __hip_atomic_load(gen, __ATOMIC_RELAXED, __HIP_MEMORY_SCOPE_AGENT);
    int v = __hip_atomic_fetch_add(cnt, 1, __ATOMIC_ACQ_REL, __HIP_MEMORY_SCOPE_AGENT);
    if (v == (int)gridDim.x - 1){
      __hip_atomic_store(cnt, 0, __ATOMIC_RELAXED, __HIP_MEMORY_SCOPE_AGENT);
      __hip_atomic_fetch_add(gen, 1, __ATOMIC_ACQ_REL, __HIP_MEMORY_SCOPE_AGENT);
    } else {
      while (__hip_atomic_load(gen, __ATOMIC_ACQUIRE, __HIP_MEMORY_SCOPE_AGENT) == g){
        __builtin_amdgcn_s_sleep(8);
      }
    }
    __threadfence();
  }
  __syncthreads();
}

// ---------------------------------------------------------------- front: fps (blocks 0..3) || cvt_all (rest)
__global__ __launch_bounds__(256) void front_kernel(const float* __restrict__ pts,
    float* __restrict__ center,
    const float* __restrict__ s0, const float* __restrict__ s1,
    const float* __restrict__ s2, const float* __restrict__ s3,
    const float* __restrict__ s4, const float* __restrict__ s5,
    bf16* __restrict__ dst){
  __shared__ float4 P[1024];
  __shared__ ull red[2][4];
  if (blockIdx.x >= Bn){
    long i = ((long)(blockIdx.x - Bn)*256 + threadIdx.x)*4;
    if (i >= 11624448L) return;
    const float* s; long off;
    if      (i <  7077888L){ s = s0; off = 0L; }
    else if (i < 10616832L){ s = s1; off =  7077888L; }
    else if (i < 11132928L){ s = s2; off = 10616832L; }
    else if (i < 11165696L){ s = s3; off = 11132928L; }
    else if (i < 11427840L){ s = s4; off = 11165696L; }
    else                   { s = s5; off = 11427840L; }
    float4 v = *(const float4*)(s + (i - off));
    short* o = (short*)dst + i;
    o[0] = f2bf(v.x); o[1] = f2bf(v.y); o[2] = f2bf(v.z); o[3] = f2bf(v.w);
    return;
  }
  int b = blockIdx.x, t = threadIdx.x;
  int w = t >> 6, lane = t & 63;
  const float* p = pts + (size_t)b * Np * 3;
  float X[4], Y[4], Z[4], D[4];
  #pragma unroll
  for (int i = 0; i < 4; ++i){
    int n = t + 256*i;
    float a = p[n*3+0], c = p[n*3+1], e = p[n*3+2];
    X[i] = a; Y[i] = c; Z[i] = e;
    P[n] = make_float4(a, c, e, 0.f);
    D[i] = 1e10f;
  }
  __syncthreads();
  float4 c0 = P[0];
  float px = c0.x, py = c0.y, pz = c0.z;
  if (t == 0){
    center[(size_t)(b*Gn)*3+0] = px;
    center[(size_t)(b*Gn)*3+1] = py;
    center[(size_t)(b*Gn)*3+2] = pz;
  }
  for (int it = 1; it < Gn; ++it){
    float v = -1.f; int nbest = t;
    #pragma unroll
    for (int i = 0; i < 4; ++i){
      float dx = __fsub_rn(X[i], px);
      float dy = __fsub_rn(Y[i], py);
      float dz = __fsub_rn(Z[i], pz);
      float d  = __fadd_rn(__fadd_rn(__fmul_rn(dx,dx), __fmul_rn(dy,dy)), __fmul_rn(dz,dz));
      float dm = fminf(D[i], d); D[i] = dm;
      if (dm > v){ v = dm; nbest = t + 256*i; }
    }
    ull key = ((ull)__float_as_uint(v) << 32) | (unsigned)(Np-1 - nbest);
    key = redmax64(key);
    if (lane == 63) red[it & 1][w] = key;
    __syncthreads();
    ull k = umax64(umax64(red[it & 1][0], red[it & 1][1]),
                   umax64(red[it & 1][2], red[it & 1][3]));
    int wn = Np-1 - (int)(unsigned)(k & 0xFFFFFFFFu);
    wn = min(max(wn, 0), Np-1);
    float4 cc = P[wn];
    px = cc.x; py = cc.y; pz = cc.z;
    if (t == 0){
      center[(size_t)(b*Gn+it)*3+0] = px;
      center[(size_t)(b*Gn+it)*3+1] = py;
      center[(size_t)(b*Gn+it)*3+2] = pz;
    }
  }
}

// ---------------------------------------------------------------- KNN
__global__ __launch_bounds__(256) void knn_kernel(const float* __restrict__ pts,
                                                  const float* __restrict__ center,
                                                  float* __restrict__ nb){
  int gid = blockIdx.x; int b = gid >> 7;
  __shared__ float d2[1024];
  __shared__ float rv[4]; __shared__ int ri[4];
  int t = threadIdx.x;
  float cx = center[(size_t)gid*3+0], cy = center[(size_t)gid*3+1], cz = center[(size_t)gid*3+2];
  const float* p = pts + (size_t)b * Np * 3;
  for (int n = t; n < Np; n += 256){
    float dx = __fsub_rn(cx, p[n*3+0]);
    float dy = __fsub_rn(cy, p[n*3+1]);
    float dz = __fsub_rn(cz, p[n*3+2]);
    d2[n] = __fadd_rn(__fadd_rn(__fmul_rn(dx,dx), __fmul_rn(dy,dy)), __fmul_rn(dz,dz));
  }
  __syncthreads();
  for (int kk = 0; kk < Kn; ++kk){
    float v = 3e38f; int idx = 0;
    for (int n = t; n < Np; n += 256){
      float d = d2[n];
      if (d < v || (d == v && n < idx)){ v = d; idx = n; }
    }
    ull key = ((ull)(unsigned)(~__float_as_uint(v)) << 32) | (unsigned)(Np-1 - idx);
    key = redmax64(key);
    if ((t & 63) == 63){
      rv[t>>6] = __uint_as_float(~(unsigned)(key >> 32));
      ri[t>>6] = Np-1 - (int)(unsigned)(key & 0xFFFFFFFFu);
    }
    __syncthreads();
    if (t == 0){
      float bv = rv[0]; int bi = ri[0];
      for (int w = 1; w < 4; ++w){
        if (rv[w] < bv || (rv[w] == bv && ri[w] < bi)){ bv = rv[w]; bi = ri[w]; }
      }
      bi = min(max(bi, 0), Np-1);
      nb[((size_t)gid*Kn+kk)*3+0] = __fsub_rn(p[bi*3+0], cx);
      nb[((size_t)gid*Kn+kk)*3+1] = __fsub_rn(p[bi*3+1], cy);
      nb[((size_t)gid*Kn+kk)*3+2] = __fsub_rn(p[bi*3+2], cz);
      d2[bi] = 3e38f;
    }
    __syncthreads();
  }
}

// ---------------------------------------------------------------- enc2: fused enc1 (3->128, bn+relu) + GEMM(128->256) + group-max
template<typename WT>
__global__ __launch_bounds__(256) void enc2_kernel(const float* __restrict__ nb,
    const float* __restrict__ w1, const float* __restrict__ b1,
    const float* __restrict__ g1, const float* __restrict__ bb1,
    const WT* __restrict__ W2, const float* __restrict__ b2,
    bf16* __restrict__ F3b){
  __shared__ __align__(16) short As[64*72];
  __shared__ __align__(16) short Ws[128*72];
  __shared__ float w1s0[128], w1s1[128], w1s2[128], sa[128], sc[128];
  int bm = blockIdx.x * 64, bn = blockIdx.y * 128;
  int t = threadIdx.x;
  int row = t >> 2, kseg = (t & 3) * 16;
  int row2 = t >> 1, kseg2 = (t & 1) * 32;
  int w = t >> 6, lane = t & 63, m16 = lane & 15, q = lane >> 4;
  if (t < 128){
    float a = g1[t] * BNS;
    w1s0[t] = w1[t*3+0]; w1s1[t] = w1[t*3+1]; w1s2[t] = w1[t*3+2];
    sa[t] = a; sc[t] = b1[t]*a + bb1[t];
  }
  const float* nbr = nb + (size_t)(bm + row)*3;
  float p0 = nbr[0], p1 = nbr[1], p2 = nbr[2];
  __syncthreads();
  floatx4 acc[8] = {};
  for (int k0 = 0; k0 < 128; k0 += 64){
    {
      short* dstp = &As[row*72 + kseg];
      #pragma unroll
      for (int j = 0; j < 16; ++j){
        int c = k0 + kseg + j;
        float v = p0*w1s0[c] + p1*w1s1[c] + p2*w1s2[c];
        v = fmaxf(v*sa[c] + sc[c], 0.f);
        dstp[j] = f2bf(v);
      }
    }
    {
      int n = bn + row2;
      if constexpr (sizeof(WT) == 2){
        const short* Wr = (const short*)W2 + (size_t)n*128 + k0 + kseg2;
        *(short8*)&Ws[row2*72 + kseg2]      = *(const short8*)Wr;
        *(short8*)&Ws[row2*72 + kseg2 + 8]  = *(const short8*)(Wr + 8);
        *(short8*)&Ws[row2*72 + kseg2 + 16] = *(const short8*)(Wr + 16);
        *(short8*)&Ws[row2*72 + kseg2 + 24] = *(const short8*)(Wr + 24);
      } else {
        const float* Wr = (const float*)W2 + (size_t)n*128 + k0 + kseg2;
        float wv[32];
        #pragma unroll
        for (int j = 0; j < 8; ++j) *(float4*)&wv[j*4] = *(const float4*)(Wr + j*4);
        short* dstp = &Ws[row2*72 + kseg2];
        #pragma unroll
        for (int jj = 0; jj < 32; ++jj) dstp[jj] = f2bf(wv[jj]);
      }
    }
    __syncthreads();
    short8 af0 = *(const short8*)&As[(w*16 + m16)*72 + q*8];
    short8 af1 = *(const short8*)&As[(w*16 + m16)*72 + 32 + q*8];
    #pragma unroll
    for (int j = 0; j < 8; ++j){
      short8 b0 = *(const short8*)&Ws[(j*16 + m16)*72 + q*8];
      acc[j] = __builtin_amdgcn_mfma_f32_16x16x32_bf16(af0, b0, acc[j], 0, 0, 0);
      short8 b1v = *(const short8*)&Ws[(j*16 + m16)*72 + 32 + q*8];
      acc[j] = __builtin_amdgcn_mfma_f32_16x16x32_bf16(af1, b1v, acc[j], 0, 0, 0);
    }
    __syncthreads();
  }
  float val[8][4];
  #pragma unroll
  for (int j = 0; j < 8; ++j){
    int n = bn + j*16 + m16;
    float bv = b2[n];
    #pragma unroll
    for (int r = 0; r < 4; ++r) val[j][r] = acc[j][r] + bv;
  }
  float* mat = (float*)As;
  #pragma unroll
  for (int j = 0; j < 8; ++j){
    float lm = fmaxf(fmaxf(val[j][0], val[j][1]), fmaxf(val[j][2], val[j][3]));
    mat[(w*4 + q)*128 + j*16 + m16] = lm;
  }
  bf16* C = F3b + 256;
  #pragma unroll
  for (int j = 0; j < 8; ++j){
    int n = bn + j*16 + m16;
    #pragma unroll
    for (int r = 0; r < 4; ++r){
      int m = bm + w*16 + q*4 + r;
      C[(size_t)m*512 + n] = __float2bfloat16(val[j][r]);
    }
  }
  __syncthreads();
  int col = t & 127, half = t >> 7;
  float gm = mat[(half*8)*128 + col];
  #pragma unroll
  for (int s = 1; s < 8; ++s) gm = fmaxf(gm, mat[(half*8 + s)*128 + col]);
  bf16 gb = __float2bfloat16(gm);
  bf16* dstm = F3b + (size_t)(bm + half*32)*512 + bn + col;
  #pragma unroll
  for (int rr = 0; rr < 32; ++rr) dstm[(size_t)rr*512] = gb;
}

// ---------------------------------------------------------------- MFMA GEMM 64x128, BK=64
template<typename AT, typename WT, int ACT, typename CT, int POOL>
__global__ __launch_bounds__(256) void gemm_mfma128(const AT* __restrict__ A, int lda,
                                                    const WT* __restrict__ W,
                                                    const float* __restrict__ bias,
                                                    const float* __restrict__ gz,
                                                    const float* __restrict__ bbp,
                                                    CT* __restrict__ C, int ldc,
                                                    int M, int N, int K){
  __shared__ __align__(16) short As[64*72];
  __shared__ __align__(16) short Ws[128*72];
  int bm = blockIdx.x * 64, bn = blockIdx.y * 128;
  int t = threadIdx.x;
  int row = t >> 2, kseg = (t & 3) * 16;
  int row2 = t >> 1, kseg2 = (t & 1) * 32;
  int w = t >> 6, lane = t & 63, m16 = lane & 15, q = lane >> 4;
  floatx4 acc[8] = {};
  for (int k0 = 0; k0 < K; k0 += 64){
    if constexpr (sizeof(AT) == 2){
      const short* Ar = (const short*)A + (size_t)(bm + row)*lda + k0 + kseg;
      *(short8*)&As[row*72 + kseg]     = *(const short8*)Ar;
      *(short8*)&As[row*72 + kseg + 8] = *(const short8*)(Ar + 8);
    } else {
      const float* Ar = (const float*)A + (size_t)(bm + row)*lda + k0 + kseg;
      float a[16];
      #pragma unroll
      for (int j = 0; j < 4; ++j) *(float4*)&a[j*4] = *(const float4*)(Ar + j*4);
      short* dstp = &As[row*72 + kseg];
      #pragma unroll
      for (int jj = 0; jj < 16; ++jj) dstp[jj] = f2bf(a[jj]);
    }
    {
      int n = bn + row2;
      if constexpr (sizeof(WT) == 2){
        short8 v0, v1, v2, v3;
        #pragma unroll
        for (int j = 0; j < 8; ++j){ v0[j] = 0; v1[j] = 0; v2[j] = 0; v3[j] = 0; }
        if (n < N){
          const short* Wr = (const short*)W + (size_t)n*K + k0 + kseg2;
          v0 = *(const short8*)Wr;
          v1 = *(const short8*)(Wr + 8);
          v2 = *(const short8*)(Wr + 16);
          v3 = *(const short8*)(Wr + 24);
        }
        *(short8*)&Ws[row2*72 + kseg2]      = v0;
        *(short8*)&Ws[row2*72 + kseg2 + 8]  = v1;
        *(short8*)&Ws[row2*72 + kseg2 + 16] = v2;
        *(short8*)&Ws[row2*72 + kseg2 + 24] = v3;
      } else {
        short* dstp = &Ws[row2*72 + kseg2];
        if (n < N){
          const float* Wr = (const float*)W + (size_t)n*K + k0 + kseg2;
          float wv[32];
          #pragma unroll
          for (int j = 0; j < 8; ++j) *(float4*)&wv[j*4] = *(const float4*)(Wr + j*4);
          #pragma unroll
          for (int jj = 0; jj < 32; ++jj) dstp[jj] = f2bf(wv[jj]);
        } else {
          #pragma unroll
          for (int jj = 0; jj < 32; ++jj) dstp[jj] = 0;
        }
      }
    }
    __syncthreads();
    short8 af0 = *(const short8*)&As[(w*16 + m16)*72 + q*8];
    short8 af1 = *(const short8*)&As[(w*16 + m16)*72 + 32 + q*8];
    #pragma unroll
    for (int j = 0; j < 8; ++j){
      short8 b0 = *(const short8*)&Ws[(j*16 + m16)*72 + q*8];
      acc[j] = __builtin_amdgcn_mfma_f32_16x16x32_bf16(af0, b0, acc[j], 0, 0, 0);
      short8 b1 = *(const short8*)&Ws[(j*16 + m16)*72 + 32 + q*8];
      acc[j] = __builtin_amdgcn_mfma_f32_16x16x32_bf16(af1, b1, acc[j], 0, 0, 0);
    }
    __syncthreads();
  }
  float val[8][4];
  #pragma unroll
  for (int j = 0; j < 8; ++j){
    int n = bn + j*16 + m16;
    float bv = (bias && n < N) ? bias[n] : 0.f;
    float gv = 0.f, bbv = 0.f;
    if (ACT == 1 && n < N){ gv = gz[n] * BNS; bbv = bbp[n]; }
    #pragma unroll
    for (int r = 0; r < 4; ++r){
      float v = acc[j][r] + bv;
      if (ACT == 1){ v = v * gv + bbv; v = fmaxf(v, 0.f); }
      val[j][r] = v;
    }
  }
  if constexpr (POOL == 0){
    #pragma unroll
    for (int j = 0; j < 8; ++j){
      int n = bn + j*16 + m16;
      if (n < N){
        #pragma unroll
        for (int r = 0; r < 4; ++r){
          int m = bm + w*16 + q*4 + r;
          if constexpr (sizeof(CT) == 2) C[(size_t)m*ldc + n] = __float2bfloat16(val[j][r]);
          else                           C[(size_t)m*ldc + n] = val[j][r];
        }
      }
    }
  } else {
    float* mat = (float*)As;
    #pragma unroll
    for (int j = 0; j < 8; ++j){
      float lm = fmaxf(fmaxf(val[j][0], val[j][1]), fmaxf(val[j][2], val[j][3]));
      mat[(w*4 + q)*128 + j*16 + m16] = lm;
    }
    __syncthreads();
    int col = t & 127, half = t >> 7;
    float gm = mat[(half*8)*128 + col];
    #pragma unroll
    for (int s = 1; s < 8; ++s) gm = fmaxf(gm, mat[(half*8 + s)*128 + col]);
    int g = (bm >> 5) + half;
    ((float*)C)[(size_t)g*ldc + bn + col] = gm;
  }
}

// ---------------------------------------------------------------- MFMA GEMM 64x64, BK=64 (small-path out_proj MODE1)
template<typename AT, typename WT, int ACT, int MODE, typename CT = float>
__global__ __launch_bounds__(256) void gemm_mfma64(const AT* __restrict__ A, int lda,
                                                   const WT* __restrict__ W,
                                                   const float* __restrict__ bias,
                                                   const float* __restrict__ gz,
                                                   const float* __restrict__ bbp,
                                                   CT* __restrict__ C, int ldc,
                                                   int M, int N, int K){
  __shared__ __align__(16) short As[64*72];
  __shared__ __align__(16) short Ws[64*72];
  int bm = blockIdx.x * 64, bn = blockIdx.y * 64;
  int t = threadIdx.x;
  int row = t >> 2, kseg = (t & 3) * 16;
  int w = t >> 6, lane = t & 63, m16 = lane & 15, q = lane >> 4;
  floatx4 acc[4] = {};
  for (int k0 = 0; k0 < K; k0 += 64){
    if constexpr (MODE == 1){
      const float* Yr = (const float*)A + (size_t)(bm + row)*lda + k0 + kseg;
      const float* Zr = gz + (size_t)(bm + row)*1536 + 768 + k0 + kseg;
      float y[16], z[16];
      #pragma unroll
      for (int j = 0; j < 4; ++j){
        *(float4*)&y[j*4] = *(const float4*)(Yr + j*4);
        *(float4*)&z[j*4] = *(const float4*)(Zr + j*4);
      }
      short* dstp = &As[row*72 + kseg];
      #pragma unroll
      for (int jj = 0; jj < 16; ++jj) dstp[jj] = f2bf(y[jj] * (z[jj] * fsig(z[jj])));
    } else if constexpr (sizeof(AT) == 2){
      const short* Ar = (const short*)A + (size_t)(bm + row)*lda + k0 + kseg;
      *(short8*)&As[row*72 + kseg]     = *(const short8*)Ar;
      *(short8*)&As[row*72 + kseg + 8] = *(const short8*)(Ar + 8);
    } else {
      const float* Ar = (const float*)A + (size_t)(bm + row)*lda + k0 + kseg;
      float a[16];
      #pragma unroll
      for (int j = 0; j < 4; ++j) *(float4*)&a[j*4] = *(const float4*)(Ar + j*4);
      short* dstp = &As[row*72 + kseg];
      #pragma unroll
      for (int jj = 0; jj < 16; ++jj) dstp[jj] = f2bf(a[jj]);
    }
    {
      int n = bn + row;
      if constexpr (sizeof(WT) == 2){
        short8 v0, v1;
        #pragma unroll
        for (int j = 0; j < 8; ++j){ v0[j] = 0; v1[j] = 0; }
        if (n < N){
          const short* Wr = (const short*)W + (size_t)n*K + k0 + kseg;
          v0 = *(const short8*)Wr;
          v1 = *(const short8*)(Wr + 8);
        }
        *(short8*)&Ws[row*72 + kseg]     = v0;
        *(short8*)&Ws[row*72 + kseg + 8] = v1;
      } else {
        short* dstp = &Ws[row*72 + kseg];
        if (n < N){
          const float* Wr = (const float*)W + (size_t)n*K + k0 + kseg;
          float wv[16];
          #pragma unroll
          for (int j = 0; j < 4; ++j) *(float4*)&wv[j*4] = *(const float4*)(Wr + j*4);
          #pragma unroll
          for (int jj = 0; jj < 16; ++jj) dstp[jj] = f2bf(wv[jj]);
        } else {
          #pragma unroll
          for (int jj = 0; jj < 16; ++jj) dstp[jj] = 0;
        }
      }
    }
    __syncthreads();
    short8 af0 = *(const short8*)&As[(w*16 + m16)*72 + q*8];
    short8 af1 = *(const short8*)&As[(w*16 + m16)*72 + 32 + q*8];
    #pragma unroll
    for (int j = 0; j < 4; ++j){
      short8 b0 = *(const short8*)&Ws[(j*16 + m16)*72 + q*8];
      acc[j] = __builtin_amdgcn_mfma_f32_16x16x32_bf16(af0, b0, acc[j], 0, 0, 0);
      short8 b1 = *(const short8*)&Ws[(j*16 + m16)*72 + 32 + q*8];
      acc[j] = __builtin_amdgcn_mfma_f32_16x16x32_bf16(af1, b1, acc[j], 0, 0, 0);
    }
    __syncthreads();
  }
  #pragma unroll
  for (int j = 0; j < 4; ++j){
    int n = bn + j*16 + m16;
    if (n < N){
      float bv = bias ? bias[n] : 0.f;
      #pragma unroll
      for (int r = 0; r < 4; ++r){
        int m = bm + w*16 + q*4 + r;
        float v = acc[j][r] + bv;
        if constexpr (sizeof(CT) == 2) C[(size_t)m*ldc + n] = __float2bfloat16(v);
        else                           C[(size_t)m*ldc + n] = v;
      }
    }
  }
}

// ---------------------------------------------------------------- x_proj GEMM, fused conv+silu (small path)
template<typename WT>
__global__ __launch_bounds__(256) void xproj_kernel(const float* __restrict__ xz,
                                                    const WT* __restrict__ W,
                                                    const float* __restrict__ cw,
                                                    const float* __restrict__ cb,
                                                    float* __restrict__ xdbp,
                                                    int KB){
  __shared__ __align__(16) short As[64*72];
  __shared__ __align__(16) short Ws[64*72];
  int bm = blockIdx.x * 64;
  int ks = blockIdx.y;
  int t = threadIdx.x;
  int row = t >> 2, kseg = (t & 3) * 16;
  int w = t >> 6, lane = t & 63, m16 = lane & 15, q = lane >> 4;
  int m = bm + row;
  int l = m % Ln;
  const int kbase = ks * KB;
  floatx4 acc[4] = {};
  const float4 z4 = make_float4(0.f, 0.f, 0.f, 0.f);
  for (int k0 = kbase; k0 < kbase + KB; k0 += 64){
    {
      int ch = k0 + kseg;
      const float* base = xz + (size_t)m*1536 + ch;
      float x0[16], x1[16], x2[16], x3[16];
      #pragma unroll
      for (int j4 = 0; j4 < 4; ++j4){
        *(float4*)&x3[j4*4] = *(const float4*)(base + j4*4);
        *(float4*)&x2[j4*4] = (l >= 1) ? *(const float4*)(base - 1536 + j4*4) : z4;
        *(float4*)&x1[j4*4] = (l >= 2) ? *(const float4*)(base - 2*1536 + j4*4) : z4;
        *(float4*)&x0[j4*4] = (l >= 3) ? *(const float4*)(base - 3*1536 + j4*4) : z4;
      }
      short* dstp = &As[row*72 + kseg];
      #pragma unroll
      for (int j = 0; j < 16; ++j){
        float4 wv = *(const float4*)(cw + (size_t)(ch + j)*4);
        float v = x0[j]*wv.x + x1[j]*wv.y + x2[j]*wv.z + x3[j]*wv.w + cb[ch + j];
        v = v * fsig(v);
        dstp[j] = f2bf(v);
      }
    }
    {
      int n = row;
      if constexpr (sizeof(WT) == 2){
        short8 v0, v1;
        #pragma unroll
        for (int j = 0; j < 8; ++j){ v0[j] = 0; v1[j] = 0; }
        if (n < 56){
          const short* Wr = (const short*)W + (size_t)n*DI + k0 + kseg;
          v0 = *(const short8*)Wr;
          v1 = *(const short8*)(Wr + 8);
        }
        *(short8*)&Ws[row*72 + kseg]     = v0;
        *(short8*)&Ws[row*72 + kseg + 8] = v1;
      } else {
        short* dstp = &Ws[row*72 + kseg];
        if (n < 56){
          const float* Wr = (const float*)W + (size_t)n*DI + k0 + kseg;
          float wv[16];
          #pragma unroll
          for (int j = 0; j < 4; ++j) *(float4*)&wv[j*4] = *(const float4*)(Wr + j*4);
          #pragma unroll
          for (int jj = 0; jj < 16; ++jj) dstp[jj] = f2bf(wv[jj]);
        } else {
          #pragma unroll
          for (int jj = 0; jj < 16; ++jj) dstp[jj] = 0;
        }
      }
    }
    __syncthreads();
    short8 af0 = *(const short8*)&As[(w*16 + m16)*72 + q*8];
    short8 af1 = *(const short8*)&As[(w*16 + m16)*72 + 32 + q*8];
    #pragma unroll
    for (int j = 0; j < 4; ++j){
      short8 b0 = *(const short8*)&Ws[(j*16 + m16)*72 + q*8];
      acc[j] = __builtin_amdgcn_mfma_f32_16x16x32_bf16(af0, b0, acc[j], 0, 0, 0);
      short8 b1 = *(const short8*)&Ws[(j*16 + m16)*72 + 32 + q*8];
      acc[j] = __builtin_amdgcn_mfma_f32_16x16x32_bf16(af1, b1, acc[j], 0, 0, 0);
    }
    __syncthreads();
  }
  float* C = xdbp + (size_t)ks * XDBS;
  #pragma unroll
  for (int j = 0; j < 4; ++j){
    int n = j*16 + m16;
    if (n < 56){
      #pragma unroll
      for (int r = 0; r < 4; ++r){
        int mm = bm + w*16 + q*4 + r;
        C[(size_t)mm*56 + n] = acc[j][r];
      }
    }
  }
}

// -------------------------------------------------- pos || sort
__global__ __launch_bounds__(128) void pos_sort_kernel(const float* __restrict__ center,
    const float* __restrict__ w1, const float* __restrict__ b1,
    const float* __restrict__ w2, const float* __restrict__ b2,
    float* __restrict__ tok, int* __restrict__ order){
  __shared__ float h1[128]; __shared__ float c3[3];
  __shared__ float key[128];
  int t = threadIdx.x;
  if (blockIdx.x < Bn*Gn){
    int gid = blockIdx.x;
    if (t < 3) c3[t] = center[(size_t)gid*3 + t];
    __syncthreads();
    float a = w1[t*3+0]*c3[0] + w1[t*3+1]*c3[1] + w1[t*3+2]*c3[2] + b1[t];
    h1[t] = 0.5f * a * (1.f + erff(a * 0.70710678118654752440f));
    __syncthreads();
    for (int c = t; c < DM; c += 128){
      float s = b2[c];
      for (int j = 0; j < 128; ++j) s += w2[(size_t)c*128 + j] * h1[j];
      tok[(size_t)gid*DM + c] += s;
    }
  } else {
    int bax = blockIdx.x - Bn*Gn; int b = bax / 3, ax = bax % 3;
    key[t] = center[(size_t)(b*Gn + t)*3 + ax];
    __syncthreads();
    float kt = key[t]; int r = 0;
    for (int j = 0; j < Gn; ++j){
      float kj = key[j];
      r += (kj < kt || (kj == kt && j < t)) ? 1 : 0;
    }
    r = min(max(r, 0), Gn-1);
    order[b*Ln + ax*Gn + r] = t;
  }
}

// -------------------------------------------------- legacy small-path kernels
__global__ __launch_bounds__(256) void ln_res_first(const float* __restrict__ tok,
                                                    const int* __restrict__ order,
                                                    float* __restrict__ res,
                                                    bf16* __restrict__ x,
                                                    const float* __restrict__ w,
                                                    const float* __restrict__ bias){
  int wv = threadIdx.x >> 6, ln = threadIdx.x & 63;
  int tokid = blockIdx.x*4 + wv;
  int b = tokid / Ln;
  int src = order[tokid];
  src = min(max(src, 0), Gn-1);
  const float* hr = tok + ((size_t)(b*Gn + src))*DM;
  float* rr = res + (size_t)tokid*DM;
  bf16* xr = x + (size_t)tokid*DM;
  float v[6]; float s = 0.f;
  #pragma unroll
  for (int i = 0; i < 6; ++i){ int c = ln + 64*i; float t = hr[c]; rr[c] = t; v[i] = t; s += t; }
  #pragma unroll
  for (int o = 32; o > 0; o >>= 1) s += __shfl_xor(s, o);
  float mu = s * (1.f/DM);
  float q = 0.f;
  #pragma unroll
  for (int i = 0; i < 6; ++i){ float d = v[i] - mu; q += d*d; }
  #pragma unroll
  for (int o = 32; o > 0; o >>= 1) q += __shfl_xor(q, o);
  float rstd = rsqrtf(q * (1.f/DM) + EPSf);
  #pragma unroll
  for (int i = 0; i < 6; ++i){ int c = ln + 64*i;
    xr[c] = __float2bfloat16((v[i]-mu)*rstd*w[c] + bias[c]); }
}

__global__ __launch_bounds__(256) void ln_res_kernel(const float* __restrict__ h,
                                                     float* __restrict__ res,
                                                     bf16* __restrict__ x,
                                                     const float* __restrict__ w,
                                                     const float* __restrict__ bias){
  int wv = threadIdx.x >> 6, ln = threadIdx.x & 63;
  int tokid = blockIdx.x*4 + wv;
  const float* hr = h + (size_t)tokid*DM;
  float* rr = res + (size_t)tokid*DM;
  bf16* xr = x + (size_t)tokid*DM;
  float v[6]; float s = 0.f;
  #pragma unroll
  for (int i = 0; i < 6; ++i){ int c = ln + 64*i; float t = hr[c] + rr[c]; rr[c] = t; v[i] = t; s += t; }
  #pragma unroll
  for (int o = 32; o > 0; o >>= 1) s += __shfl_xor(s, o);
  float mu = s * (1.f/DM);
  float q = 0.f;
  #pragma unroll
  for (int i = 0; i < 6; ++i){ float d = v[i] - mu; q += d*d; }
  #pragma unroll
  for (int o = 32; o > 0; o >>= 1) q += __shfl_xor(q, o);
  float rstd = rsqrtf(q * (1.f/DM) + EPSf);
  #pragma unroll
  for (int i = 0; i < 6; ++i){ int c = ln + 64*i;
    xr[c] = __float2bfloat16((v[i]-mu)*rstd*w[c] + bias[c]); }
}

__global__ __launch_bounds__(256) void scanA_kernel(const float* __restrict__ xz,
                                                    const float* __restrict__ xdbp, int nks,
                                                    const float* __restrict__ cw,
                                                    const float* __restrict__ cb,
                                                    const float* __restrict__ dpw,
                                                    const float* __restrict__ dpb,
                                                    const float* __restrict__ A_log,
                                                    float* __restrict__ SB_S,
                                                    float* __restrict__ SB_dt,
                                                    float* __restrict__ BND){
  __shared__ float sRow[CHS*56];
  __shared__ float sU[CHS*256];
  int blk = blockIdx.x;
  int c = blk % NCH; int bd = blk / NCH; int dch = bd % 3; int b = bd / 3;
  int t = threadIdx.x; int d = dch*256 + t;
  int l0 = c*CHS;
  for (int i = t; i < CHS*56; i += 256){
    size_t base = ((size_t)(b*Ln + l0))*56 + i;
    float s = xdbp[base];
    for (int k = 1; k < nks; ++k) s += xdbp[(size_t)k*XDBS + base];
    sRow[i] = s;
  }
  float xv[CHS+3];
  #pragma unroll
  for (int j = 0; j < 3; ++j){
    int ll = l0 - 3 + j;
    xv[j] = (ll >= 0) ? xz[((size_t)(b*Ln + ll))*1536 + d] : 0.f;
  }
  const float* xp = xz + ((size_t)(b*Ln + l0))*1536 + d;
  #pragma unroll
  for (int i = 0; i < CHS; ++i) xv[3+i] = xp[(size_t)i*1536];
  #pragma unroll
  for (int j = 0; j < 3; ++j) BND[((size_t)blk*3 + j)*256 + t] = xv[j];
  float cw0 = cw[d*4+0], cw1 = cw[d*4+1], cw2 = cw[d*4+2], cw3 = cw[d*4+3];
  float cbv = cb[d];
  #pragma unroll
  for (int i = 0; i < CHS; ++i){
    float v = xv[i]*cw0 + xv[i+1]*cw1 + xv[i+2]*cw2 + xv[i+3]*cw3 + cbv;
    sU[i*256 + t] = v * fsig(v);
  }
  float w[DTR];
  const float* wp = dpw + (size_t)d*DTR;
  #pragma unroll
  for (int j = 0; j < DTR; ++j) w[j] = wp[j];
  float a2[DSt], h[DSt];
  const float* ap = A_log + (size_t)d*DSt;
  #pragma unroll
  for (int s = 0; s < DSt; ++s){ a2[s] = -__expf(ap[s]) * LOG2E; h[s] = 0.f; }
  float dbias = dpb[d];
  float sumdt = 0.f;
  __syncthreads();
  for (int i = 0; i < CHS; ++i){
    int ro = i*56;
    float dtr = dbias;
    #pragma unroll
    for (int j = 0; j < DTR; ++j) dtr += w[j] * sRow[ro + j];
    float dtv = fsoftplus(dtr);
    sumdt += dtv;
    float du = dtv * sU[i*256 + t];
    #pragma unroll
    for (int s = 0; s < DSt; ++s)
      h[s] = exp2f(dtv * a2[s]) * h[s] + du * sRow[ro + 24 + s];
  }
  size_t sb = ((size_t)blk*256 + t)*16;
  #pragma unroll
  for (int s = 0; s < DSt; ++s) SB_S[sb + s] = h[s];
  SB_dt[(size_t)blk*256 + t] = sumdt;
}

__global__ __launch_bounds__(256) void scanB_kernel(float* __restrict__ xz,
                                                    const float* __restrict__ xdbp, int nks,
                                                    const float* __restrict__ cw,
                                                    const float* __restrict__ cb,
                                                    const float* __restrict__ dpw,
                                                    const float* __restrict__ dpb,
                                                    const float* __restrict__ A_log,
                                                    const float* __restrict__ Dp,
                                                    const float* __restrict__ SB_S,
                                                    const float* __restrict__ SB_dt,
                                                    const float* __restrict__ BND){
  __shared__ float sRow[CHS*56];
  __shared__ float sU[CHS*256];
  int blk = blockIdx.x;
  int c = blk % NCH; int bd = blk / NCH; int dch = bd % 3; int b = bd / 3;
  int t = threadIdx.x; int d = dch*256 + t;
  int l0 = c*CHS;
  for (int i = t; i < CHS*56; i += 256){
    size_t base = ((size_t)(b*Ln + l0))*56 + i;
    float s = xdbp[base];
    for (int k = 1; k < nks; ++k) s += xdbp[(size_t)k*XDBS + base];
    sRow[i] = s;
  }
  float xv[CHS+3];
  #pragma unroll
  for (int j = 0; j < 3; ++j) xv[j] = BND[((size_t)blk*3 + j)*256 + t];
  const float* xp = xz + ((size_t)(b*Ln + l0))*1536 + d;
  #pragma unroll
  for (int i = 0; i < CHS; ++i) xv[3+i] = xp[(size_t)i*1536];
  float cw0 = cw[d*4+0], cw1 = cw[d*4+1], cw2 = cw[d*4+2], cw3 = cw[d*4+3];
  float cbv = cb[d];
  #pragma unroll
  for (int i = 0; i < CHS; ++i){
    float v = xv[i]*cw0 + xv[i+1]*cw1 + xv[i+2]*cw2 + xv[i+3]*cw3 + cbv;
    sU[i*256 + t] = v * fsig(v);
  }
  float w[DTR];
  const float* wp = dpw + (size_t)d*DTR;
  #pragma unroll
  for (int j = 0; j < DTR; ++j) w[j] = wp[j];
  float a2[DSt], h[DSt];
  const float* ap = A_log + (size_t)d*DSt;
  #pragma unroll
  for (int s = 0; s < DSt; ++s){ a2[s] = -__expf(ap[s]) * LOG2E; h[s] = 0.f; }
  for (int cc = 0; cc < c; ++cc){
    size_t base = (((size_t)bd*NCH + cc)*256 + t)*16;
    float sd = SB_dt[((size_t)bd*NCH + cc)*256 + t];
    #pragma unroll
    for (int s = 0; s < DSt; ++s)
      h[s] = exp2f(sd * a2[s]) * h[s] + SB_S[base + s];
  }
  float dbias = dpb[d];
  float Dd = Dp[d];
  float* ydst = xz + ((size_t)(b*Ln + l0))*1536 + dch*256;
  __syncthreads();
  for (int i = 0; i < CHS; ++i){
    int ro = i*56;
    float dtr = dbias;
    #pragma unroll
    for (int j = 0; j < DTR; ++j) dtr += w[j] * sRow[ro + j];
    float dtv = fsoftplus(dtr);
    float u = sU[i*256 + t];
    float du = dtv * u;
    float yv = 0.f;
    #pragma unroll
    for (int s = 0; s < DSt; ++s){
      h[s] = exp2f(dtv * a2[s]) * h[s] + du * sRow[ro + 24 + s];
      yv += h[s] * sRow[ro + 40 + s];
    }
    ydst[(size_t)i*1536 + t] = yv + u*Dd;
  }
}

__global__ __launch_bounds__(256) void final_ln_kernel(const float* __restrict__ h,
                                                       const float* __restrict__ res,
                                                       const float* w1, const float* b1,
                                                       const float* w2, const float* b2,
                                                       float* __restrict__ x){
  int wv = threadIdx.x >> 6, ln = threadIdx.x & 63;
  int tokid = blockIdx.x*4 + wv;
  const float* hr = h + (size_t)tokid*DM;
  const float* rr = res + (size_t)tokid*DM;
  float* xr = x + (size_t)tokid*DM;
  float v[6]; float s = 0.f;
  #pragma unroll
  for (int i = 0; i < 6; ++i){ int c = ln + 64*i; v[i] = hr[c] + rr[c]; s += v[i]; }
  #pragma unroll
  for (int o = 32; o > 0; o >>= 1) s += __shfl_xor(s, o);
  float mu = s * (1.f/DM); float q = 0.f;
  #pragma unroll
  for (int i = 0; i < 6; ++i){ float dd = v[i]-mu; q += dd*dd; }
  #pragma unroll
  for (int o = 32; o > 0; o >>= 1) q += __shfl_xor(q, o);
  float rstd = rsqrtf(q * (1.f/DM) + EPSf);
  float u[6]; float s2 = 0.f;
  #pragma unroll
  for (int i = 0; i < 6; ++i){ int c = ln + 64*i; u[i] = (v[i]-mu)*rstd*w1[c] + b1[c]; s2 += u[i]; }
  #pragma unroll
  for (int o = 32; o > 0; o >>= 1) s2 += __shfl_xor(s2, o);
  float mu2 = s2 * (1.f/DM); float q2 = 0.f;
  #pragma unroll
  for (int i = 0; i < 6; ++i){ float dd = u[i]-mu2; q2 += dd*dd; }
  #pragma unroll
  for (int o = 32; o > 0; o >>= 1) q2 += __shfl_xor(q2, o);
  float rstd2 = rsqrtf(q2 * (1.f/DM) + EPSf);
  #pragma unroll
  for (int i = 0; i < 6; ++i){ int c = ln + 64*i; xr[c] = (u[i]-mu2)*rstd2*w2[c] + b2[c]; }
}

__global__ __launch_bounds__(384) void mean_kernel(const float* __restrict__ x,
                                                   float* __restrict__ featp){
  int blk = blockIdx.x;
  int b = blk >> 2, g = blk & 3;
  int c = threadIdx.x;
  const float* xp = x + ((size_t)(b*Ln + g*96))*DM + c;
  float a0=0.f,a1=0.f,a2=0.f,a3=0.f,a4=0.f,a5=0.f,a6=0.f,a7=0.f;
  for (int l = 0; l < 96; l += 8){
    a0 += xp[(size_t)(l+0)*DM];
    a1 += xp[(size_t)(l+1)*DM];
    a2 += xp[(size_t)(l+2)*DM];
    a3 += xp[(size_t)(l+3)*DM];
    a4 += xp[(size_t)(l+4)*DM];
    a5 += xp[(size_t)(l+5)*DM];
    a6 += xp[(size_t)(l+6)*DM];
    a7 += xp[(size_t)(l+7)*DM];
  }
  featp[(size_t)blk*DM + c] = ((a0+a1)+(a2+a3)) + ((a4+a5)+(a6+a7));
}

__global__ __launch_bounds__(256) void head_mlp(const float* __restrict__ featp,
    const float* w1, const float* b1, const float* g1, const float* bb1,
    const float* w2, const float* b2, const float* g2, const float* bb2,
    const float* w3, const float* b3, float* __restrict__ out){
  int b = blockIdx.x; int t = threadIdx.x;
  __shared__ float f[DM]; __shared__ float h1[256]; __shared__ float h2[256];
  for (int i = t; i < DM; i += 256){
    f[i] = (featp[(size_t)(b*4+0)*DM + i] + featp[(size_t)(b*4+1)*DM + i]
          + featp[(size_t)(b*4+2)*DM + i] + featp[(size_t)(b*4+3)*DM + i]) * (1.f/Ln);
  }
  __syncthreads();
  {
    float a = b1[t];
    #pragma unroll 4
    for (int j = 0; j < DM; ++j) a += w1[(size_t)t*DM + j] * f[j];
    a = a * (g1[t] * BNS) + bb1[t];
    h1[t] = fmaxf(a, 0.f);
  }
  __syncthreads();
  {
    float a = b2[t];
    #pragma unroll 4
    for (int j = 0; j < 256; ++j) a += w2[(size_t)t*256 + j] * h1[j];
    a = a * (g2[t] * BNS) + bb2[t];
    h2[t] = fmaxf(a, 0.f);
  }
  __syncthreads();
  if (t < CLSn){
    float a = b3[t];
    for (int j = 0; j < 256; ++j) a += w3[(size_t)t*256 + j] * h2[j];
    out[b*CLSn + t] = a;
  }
}

// ================================================== MEGA persistent kernel (regular launch + atomic grid barrier)
__global__ __launch_bounds__(256) void mega_layers(
    const float* __restrict__ tok, const int* __restrict__ order,
    float* __restrict__ hb, float* __restrict__ resb,
    bf16* __restrict__ xb, float* __restrict__ xz,
    float* __restrict__ xdbp, float* __restrict__ xdbR,
    bf16* __restrict__ yb, float* __restrict__ SBS,
    float* __restrict__ SBdt, float* __restrict__ H0,
    int* __restrict__ syncp,
    const float* __restrict__ lnw_all, const float* __restrict__ lnb_all,
    const bf16* __restrict__ wip, const bf16* __restrict__ wxp,
    const bf16* __restrict__ wop,
    const float* __restrict__ cw_all, const float* __restrict__ cb_all,
    const float* __restrict__ dpw_all, const float* __restrict__ dpb_all,
    const float* __restrict__ Alog_all, const float* __restrict__ Dp_all,
    const float* __restrict__ normf_w, const float* __restrict__ normf_b,
    const float* __restrict__ norm_w, const float* __restrict__ norm_b,
    float* __restrict__ xf, float* __restrict__ featp,
    const float* __restrict__ hw1, const float* __restrict__ hbi1,
    const float* __restrict__ hg1, const float* __restrict__ hbb1,
    const float* __restrict__ hw2, const float* __restrict__ hbi2,
    const float* __restrict__ hg2, const float* __restrict__ hbb2,
    const float* __restrict__ hw3, const float* __restrict__ hbi3,
    float* __restrict__ outp)
{
  __shared__ __align__(16) short As[64*72];
  __shared__ __align__(16) short Ws[128*72];
  int* cnt = syncp;
  int* gen = syncp + 1;
  int t = threadIdx.x;
  int w = t >> 6, lane = t & 63, m16 = lane & 15, q = lane >> 4;
  int row = t >> 2, kseg = (t & 3) * 16;
  int row2 = t >> 1, kseg2 = (t & 1) * 32;

  for (int l = 0; l < DEPTH; ++l){
    const float* lnw  = lnw_all + (size_t)l*DM;
    const float* lnb  = lnb_all + (size_t)l*DM;
    const bf16*  ipw  = wip + (size_t)l*1536*DM;
    const bf16*  xpw  = wxp + (size_t)l*56*DI;
    const bf16*  opw  = wop + (size_t)l*DM*DI;
    const float* cw   = cw_all + (size_t)l*DI*4;
    const float* cb   = cb_all + (size_t)l*DI;
    const float* dpw  = dpw_all + (size_t)l*DI*DTR;
    const float* dpb  = dpb_all + (size_t)l*DI;
    const float* Alg  = Alog_all + (size_t)l*DI*DSt;
    const float* Dpar = Dp_all + (size_t)l*DI;

    // ---------- phase 1: ln_res (384 wu)
    for (int wu = blockIdx.x; wu < Bn*Ln/4; wu += gridDim.x){
      int wv = w, ln = lane;
      int tokid = wu*4 + wv;
      float* rr = resb + (size_t)tokid*DM;
      bf16* xr = xb + (size_t)tokid*DM;
      float v[6]; float s = 0.f;
      if (l == 0){
        int b = tokid / Ln;
        int src = order[tokid];
        src = min(max(src, 0), Gn-1);
        const float* hr = tok + ((size_t)(b*Gn + src))*DM;
        #pragma unroll
        for (int i = 0; i < 6; ++i){ int c = ln + 64*i; float tv = hr[c]; rr[c] = tv; v[i] = tv; s += tv; }
      } else {
        const float* hr = hb + (size_t)tokid*DM;
        #pragma unroll
        for (int i = 0; i < 6; ++i){ int c = ln + 64*i; float tv = hr[c] + rr[c]; rr[c] = tv; v[i] = tv; s += tv; }
      }
      #pragma unroll
      for (int o = 32; o > 0; o >>= 1) s += __shfl_xor(s, o);
      float mu = s * (1.f/DM);
      float qq = 0.f;
      #pragma unroll
      for (int i = 0; i < 6; ++i){ float d = v[i] - mu; qq += d*d; }
      #pragma unroll
      for (int o = 32; o > 0; o >>= 1) qq += __shfl_xor(qq, o);
      float rstd = rsqrtf(qq * (1.f/DM) + EPSf);
      #pragma unroll
      for (int i = 0; i < 6; ++i){ int c = ln + 64*i;
        xr[c] = __float2bfloat16((v[i]-mu)*rstd*lnw[c] + lnb[c]); }
    }
    gbar(cnt, gen);

    // ---------- phase 2: in_proj GEMM 64x128, M=1536 N=1536 K=384 (288 wu)
    for (int wu = blockIdx.x; wu < 288; wu += gridDim.x){
      int bm = (wu % 24)*64, bn = (wu / 24)*128;
      floatx4 acc[8] = {};
      for (int k0 = 0; k0 < DM; k0 += 64){
        const short* Ar = (const short*)xb + (size_t)(bm + row)*DM + k0 + kseg;
        *(short8*)&As[row*72 + kseg]     = *(const short8*)Ar;
        *(short8*)&As[row*72 + kseg + 8] = *(const short8*)(Ar + 8);
        {
          int n = bn + row2;
          const short* Wr = (const short*)ipw + (size_t)n*DM + k0 + kseg2;
          *(short8*)&Ws[row2*72 + kseg2]      = *(const short8*)Wr;
          *(short8*)&Ws[row2*72 + kseg2 + 8]  = *(const short8*)(Wr + 8);
          *(short8*)&Ws[row2*72 + kseg2 + 16] = *(const short8*)(Wr + 16);
          *(short8*)&Ws[row2*72 + kseg2 + 24] = *(const short8*)(Wr + 24);
        }
        __syncthreads();
        short8 af0 = *(const short8*)&As[(w*16 + m16)*72 + q*8];
        short8 af1 = *(const short8*)&As[(w*16 + m16)*72 + 32 + q*8];
        #pragma unroll
        for (int j = 0; j < 8; ++j){
          short8 b0 = *(const short8*)&Ws[(j*16 + m16)*72 + q*8];
          acc[j] = __builtin_amdgcn_mfma_f32_16x16x32_bf16(af0, b0, acc[j], 0, 0, 0);
          short8 b1 = *(const short8*)&Ws[(j*16 + m16)*72 + 32 + q*8];
          acc[j] = __builtin_amdgcn_mfma_f32_16x16x32_bf16(af1, b1, acc[j], 0, 0, 0);
        }
        __syncthreads();
      }
      #pragma unroll
      for (int j = 0; j < 8; ++j){
        int n = bn + j*16 + m16;
        #pragma unroll
        for (int r = 0; r < 4; ++r){
          int m = bm + w*16 + q*4 + r;
          xz[(size_t)m*1536 + n] = acc[j][r];
        }
      }
    }
    gbar(cnt, gen);

    // ---------- phase 3: xproj (288 wu = 24 m-tiles x 12 k-parts)
    for (int wu = blockIdx.x; wu < 288; wu += gridDim.x){
      int bm = (wu % 24)*64;
      int ks = wu / 24;
      int m = bm + row;
      int lpos = m % Ln;
      int k0 = ks * 64;
      floatx4 acc[4] = {};
      const float4 z4 = make_float4(0.f,0.f,0.f,0.f);
      {
        int ch = k0 + kseg;
        const float* base = xz + (size_t)m*1536 + ch;
        float x0[16], x1[16], x2[16], x3[16];
        #pragma unroll
        for (int j4 = 0; j4 < 4; ++j4){
          *(float4*)&x3[j4*4] = *(const float4*)(base + j4*4);
          *(float4*)&x2[j4*4] = (lpos >= 1) ? *(const float4*)(base - 1536 + j4*4) : z4;
          *(float4*)&x1[j4*4] = (lpos >= 2) ? *(const float4*)(base - 2*1536 + j4*4) : z4;
          *(float4*)&x0[j4*4] = (lpos >= 3) ? *(const float4*)(base - 3*1536 + j4*4) : z4;
        }
        short* dstp = &As[row*72 + kseg];
        #pragma unroll
        for (int j = 0; j < 16; ++j){
          float4 wv4 = *(const float4*)(cw + (size_t)(ch + j)*4);
          float v = x0[j]*wv4.x + x1[j]*wv4.y + x2[j]*wv4.z + x3[j]*wv4.w + cb[ch + j];
          v = v * fsig(v);
          dstp[j] = f2bf(v);
        }
        {
          int n = row;
          short8 v0, v1;
          #pragma unroll
          for (int j = 0; j < 8; ++j){ v0[j] = 0; v1[j] = 0; }
          if (n < 56){
            const short* Wr = (const short*)xpw + (size_t)n*DI + k0 + kseg;
            v0 = *(const short8*)Wr;
            v1 = *(const short8*)(Wr + 8);
          }
          *(short8*)&Ws[row*72 + kseg]     = v0;
          *(short8*)&Ws[row*72 + kseg + 8] = v1;
        }
        __syncthreads();
        short8 af0 = *(const short8*)&As[(w*16 + m16)*72 + q*8];
        short8 af1 = *(const short8*)&As[(w*16 + m16)*72 + 32 + q*8];
        #pragma unroll
        for (int j = 0; j < 4; ++j){
          short8 b0 = *(const short8*)&Ws[(j*16 + m16)*72 + q*8];
          acc[j] = __builtin_amdgcn_mfma_f32_16x16x32_bf16(af0, b0, acc[j], 0, 0, 0);
          short8 b1 = *(const short8*)&Ws[(j*16 + m16)*72 + 32 + q*8];
          acc[j] = __builtin_amdgcn_mfma_f32_16x16x32_bf16(af1, b1, acc[j], 0, 0, 0);
        }
        __syncthreads();
      }
      float* C = xdbp + (size_t)ks * XDBS;
      #pragma unroll
      for (int j = 0; j < 4; ++j){
        int n = j*16 + m16;
        if (n < 56){
          #pragma unroll
          for (int r = 0; r < 4; ++r){
            int mm = bm + w*16 + q*4 + r;
            C[(size_t)mm*56 + n] = acc[j][r];
          }
        }
      }
    }
    gbar(cnt, gen);

    // ---------- phase 4: scanA (576 wu)
    {
      float* sRow = (float*)As;
      for (int wu = blockIdx.x; wu < Bn*3*NCB; wu += gridDim.x){
        int c = wu % NCB; int bd = wu / NCB; int dch = bd % 3; int b = bd / 3;
        int d = dch*256 + t;
        int l0 = c*CHB;
        for (int i = t; i < CHB*56; i += 256){
          size_t base = ((size_t)(b*Ln + l0))*56 + i;
          float s = xdbp[base];
          for (int k = 1; k < 12; ++k) s += xdbp[(size_t)k*XDBS + base];
          sRow[i] = s;
          if (dch == 0) xdbR[base] = s;
        }
        float xv[CHB+3];
        #pragma unroll
        for (int j = 0; j < 3; ++j){
          int ll = l0 - 3 + j;
          xv[j] = (ll >= 0) ? xz[((size_t)(b*Ln + ll))*1536 + d] : 0.f;
        }
        const float* xp = xz + ((size_t)(b*Ln + l0))*1536 + d;
        #pragma unroll
        for (int i = 0; i < CHB; ++i) xv[3+i] = xp[(size_t)i*1536];
        float cw0 = cw[d*4+0], cw1 = cw[d*4+1], cw2 = cw[d*4+2], cw3 = cw[d*4+3];
        float cbv = cb[d];
        float uu[CHB];
        #pragma unroll
        for (int i = 0; i < CHB; ++i){
          float v = xv[i]*cw0 + xv[i+1]*cw1 + xv[i+2]*cw2 + xv[i+3]*cw3 + cbv;
          uu[i] = v * fsig(v);
        }
        float wv[DTR];
        const float* wp = dpw + (size_t)d*DTR;
        #pragma unroll
        for (int j = 0; j < DTR; ++j) wv[j] = wp[j];
        float a2[DSt], h[DSt];
        const float* ap = Alg + (size_t)d*DSt;
        #pragma unroll
        for (int s = 0; s < DSt; ++s){ a2[s] = -__expf(ap[s]) * LOG2E; h[s] = 0.f; }
        float dbias = dpb[d];
        float sumdt = 0.f;
        __syncthreads();
        for (int i = 0; i < CHB; ++i){
          int ro = i*56;
          float dtr = dbias;
          #pragma unroll
          for (int j = 0; j < DTR; ++j) dtr += wv[j] * sRow[ro + j];
          float dtv = fsoftplus(dtr);
          sumdt += dtv;
          float du = dtv * uu[i];
          #pragma unroll
          for (int s = 0; s < DSt; ++s)
            h[s] = exp2f(dtv * a2[s]) * h[s] + du * sRow[ro + 24 + s];
        }
        size_t sb = ((size_t)wu*256 + t)*16;
        #pragma unroll
        for (int s = 0; s < DSt; ++s) SBS[sb + s] = h[s];
        SBdt[(size_t)wu*256 + t] = sumdt;
        __syncthreads();
      }
    }
    gbar(cnt, gen);

    // ---------- phase 5: prefix (192 wu; thread per (channel,state))
    for (int wu = blockIdx.x; wu < Bn*3*16; wu += gridDim.x){
      int bd = wu >> 4;
      int dch = bd % 3;
      int tloc = t >> 4, s = t & 15;
      int tcol = (wu & 15)*16 + tloc;
      int d = dch*256 + tcol;
      float a2 = -__expf(Alg[(size_t)d*DSt + s]) * LOG2E;
      float H = 0.f;
      size_t tb = ((size_t)bd*NCB)*256 + tcol;
      for (int c = 0; c < NCB; ++c){
        size_t base = (tb + (size_t)c*256)*16 + s;
        H0[base] = H;
        float sd = SBdt[tb + (size_t)c*256];
        H = exp2f(sd * a2) * H + SBS[base];
      }
    }
    gbar(cnt, gen);

    // ---------- phase 6: scanB (576 wu)
    {
      float* sRow = (float*)As;
      for (int wu = blockIdx.x; wu < Bn*3*NCB; wu += gridDim.x){
        int c = wu % NCB; int bd = wu / NCB; int dch = bd % 3; int b = bd / 3;
        int d = dch*256 + t;
        int l0 = c*CHB;
        for (int i = t; i < CHB*56; i += 256)
          sRow[i] = xdbR[((size_t)(b*Ln + l0))*56 + i];
        float xv[CHB+3];
        #pragma unroll
        for (int j = 0; j < 3; ++j){
          int ll = l0 - 3 + j;
          xv[j] = (ll >= 0) ? xz[((size_t)(b*Ln + ll))*1536 + d] : 0.f;
        }
        const float* xp = xz + ((size_t)(b*Ln + l0))*1536 + d;
        #pragma unroll
        for (int i = 0; i < CHB; ++i) xv[3+i] = xp[(size_t)i*1536];
        float cw0 = cw[d*4+0], cw1 = cw[d*4+1], cw2 = cw[d*4+2], cw3 = cw[d*4+3];
        float cbv = cb[d];
        float uu[CHB];
        #pragma unroll
        for (int i = 0; i < CHB; ++i){
          float v = xv[i]*cw0 + xv[i+1]*cw1 + xv[i+2]*cw2 + xv[i+3]*cw3 + cbv;
          uu[i] = v * fsig(v);
        }
        float wv[DTR];
        const float* wp = dpw + (size_t)d*DTR;
        #pragma unroll
        for (int j = 0; j < DTR; ++j) wv[j] = wp[j];
        float a2[DSt], h[DSt];
        const float* ap = Alg + (size_t)d*DSt;
        #pragma unroll
        for (int s = 0; s < DSt; ++s) a2[s] = -__expf(ap[s]) * LOG2E;
        size_t hbase = ((size_t)wu*256 + t)*16;
        #pragma unroll
        for (int s = 0; s < DSt; ++s) h[s] = H0[hbase + s];
        float dbias = dpb[d];
        float Dd = Dpar[d];
        const float* zrow = xz + ((size_t)(b*Ln + l0))*1536 + 768 + d;
        bf16* ybr = yb + ((size_t)(b*Ln + l0))*DI + d;
        __syncthreads();
        for (int i = 0; i < CHB; ++i){
          int ro = i*56;
          float dtr = dbias;
          #pragma unroll
          for (int j = 0; j < DTR; ++j) dtr += wv[j] * sRow[ro + j];
          float dtv = fsoftplus(dtr);
          float u = uu[i];
          float du = dtv * u;
          float yv = 0.f;
          #pragma unroll
          for (int s = 0; s < DSt; ++s){
            h[s] = exp2f(dtv * a2[s]) * h[s] + du * sRow[ro + 24 + s];
            yv += h[s] * sRow[ro + 40 + s];
          }
          float yfull = yv + u*Dd;
          float zv = zrow[(size_t)i*1536];
          ybr[(size_t)i*DI] = __float2bfloat16(yfull * (zv * fsig(zv)));
        }
        __syncthreads();
      }
    }
    gbar(cnt, gen);

    // ---------- phase 7: out_proj GEMM 64x128, M=1536 N=384 K=768 (72 wu)
    for (int wu = blockIdx.x; wu < 72; wu += gridDim.x){
      int bm = (wu % 24)*64, bn = (wu / 24)*128;
      floatx4 acc[8] = {};
      for (int k0 = 0; k0 < DI; k0 += 64){
        const short* Ar = (const short*)yb + (size_t)(bm + row)*DI + k0 + kseg;
        *(short8*)&As[row*72 + kseg]     = *(const short8*)Ar;
        *(short8*)&As[row*72 + kseg + 8] = *(const short8*)(Ar + 8);
        {
          int n = bn + row2;
          const short* Wr = (const short*)opw + (size_t)n*DI + k0 + kseg2;
          *(short8*)&Ws[row2*72 + kseg2]      = *(const short8*)Wr;
          *(short8*)&Ws[row2*72 + kseg2 + 8]  = *(const short8*)(Wr + 8);
          *(short8*)&Ws[row2*72 + kseg2 + 16] = *(const short8*)(Wr + 16);
          *(short8*)&Ws[row2*72 + kseg2 + 24] = *(const short8*)(Wr + 24);
        }
        __syncthreads();
        short8 af0 = *(const short8*)&As[(w*16 + m16)*72 + q*8];
        short8 af1 = *(const short8*)&As[(w*16 + m16)*72 + 32 + q*8];
        #pragma unroll
        for (int j = 0; j < 8; ++j){
          short8 b0 = *(const short8*)&Ws[(j*16 + m16)*72 + q*8];
          acc[j] = __builtin_amdgcn_mfma_f32_16x16x32_bf16(af0, b0, acc[j], 0, 0, 0);
          short8 b1 = *(const short8*)&Ws[(j*16 + m16)*72 + 32 + q*8];
          acc[j] = __builtin_amdgcn_mfma_f32_16x16x32_bf16(af1, b1, acc[j], 0, 0, 0);
        }
        __syncthreads();
      }
      #pragma unroll
      for (int j = 0; j < 8; ++j){
        int n = bn + j*16 + m16;
        #pragma unroll
        for (int r = 0; r < 4; ++r){
          int m = bm + w*16 + q*4 + r;
          hb[(size_t)m*DM + n] = acc[j][r];
        }
      }
    }
    gbar(cnt, gen);
  }

  // ---------- tail phase A: final two LayerNorms (384 wu)
  for (int wu = blockIdx.x; wu < Bn*Ln/4; wu += gridDim.x){
    int wv = w, ln = lane;
    int tokid = wu*4 + wv;
    const float* hr = hb + (size_t)tokid*DM;
    const float* rr = resb + (size_t)tokid*DM;
    float* xr = xf + (size_t)tokid*DM;
    float v[6]; float s = 0.f;
    #pragma unroll
    for (int i = 0; i < 6; ++i){ int c = ln + 64*i; v[i] = hr[c] + rr[c]; s += v[i]; }
    #pragma unroll
    for (int o = 32; o > 0; o >>= 1) s += __shfl_xor(s, o);
    float mu = s * (1.f/DM); float qq = 0.f;
    #pragma unroll
    for (int i = 0; i < 6; ++i){ float dd = v[i]-mu; qq += dd*dd; }
    #pragma unroll
    for (int o = 32; o > 0; o >>= 1) qq += __shfl_xor(qq, o);
    float rstd = rsqrtf(qq * (1.f/DM) + EPSf);
    float u[6]; float s2 = 0.f;
    #pragma unroll
    for (int i = 0; i < 6; ++i){ int c = ln + 64*i; u[i] = (v[i]-mu)*rstd*normf_w[c] + normf_b[c]; s2 += u[i]; }
    #pragma unroll
    for (int o = 32; o > 0; o >>= 1) s2 += __shfl_xor(s2, o);
    float mu2 = s2 * (1.f/DM); float q2 = 0.f;
    #pragma unroll
    for (int i = 0; i < 6; ++i){ float dd = u[i]-mu2; q2 += dd*dd; }
    #pragma unroll
    for (int o = 32; o > 0; o >>= 1) q2 += __shfl_xor(q2, o);
    float rstd2 = rsqrtf(q2 * (1.f/DM) + EPSf);
    #pragma unroll
    for (int i = 0; i < 6; ++i){ int c = ln + 64*i; xr[c] = (u[i]-mu2)*rstd2*norm_w[c] + norm_b[c]; }
  }
  gbar(cnt, gen);

  // ---------- tail phase B: mean partials (16 wu)
  for (int wu = blockIdx.x; wu < Bn*4; wu += gridDim.x){
    int b = wu >> 2, g = wu & 3;
    for (int c = t; c < DM; c += 256){
      const float* xp = xf + ((size_t)(b*Ln + g*96))*DM + c;
      float a0=0.f,a1=0.f,a2=0.f,a3=0.f,a4=0.f,a5=0.f,a6=0.f,a7=0.f;
      for (int ll = 0; ll < 96; ll += 8){
        a0 += xp[(size_t)(ll+0)*DM];
        a1 += xp[(size_t)(ll+1)*DM];
        a2 += xp[(size_t)(ll+2)*DM];
        a3 += xp[(size_t)(ll+3)*DM];
        a4 += xp[(size_t)(ll+4)*DM];
        a5 += xp[(size_t)(ll+5)*DM];
        a6 += xp[(size_t)(ll+6)*DM];
        a7 += xp[(size_t)(ll+7)*DM];
      }
      featp[(size_t)wu*DM + c] = ((a0+a1)+(a2+a3)) + ((a4+a5)+(a6+a7));
    }
  }
  gbar(cnt, gen);

  // ---------- tail phase C: MLP head (4 wu)
  {
    float* shf = (float*)As;
    float* sh1 = shf + DM;
    float* sh2 = sh1 + 256;
    for (int wu = blockIdx.x; wu < Bn; wu += gridDim.x){
      for (int i = t; i < DM; i += 256){
        shf[i] = (featp[(size_t)(wu*4+0)*DM + i] + featp[(size_t)(wu*4+1)*DM + i]
                + featp[(size_t)(wu*4+2)*DM + i] + featp[(size_t)(wu*4+3)*DM + i]) * (1.f/Ln);
      }
      __syncthreads();
      {
        float a = hbi1[t];
        #pragma unroll 4
        for (int j = 0; j < DM; ++j) a += hw1[(size_t)t*DM + j] * shf[j];
        a = a * (hg1[t] * BNS) + hbb1[t];
        sh1[t] = fmaxf(a, 0.f);
      }
      __syncthreads();
      {
        float a = hbi2[t];
        #pragma unroll 4
        for (int j = 0; j < 256; ++j) a += hw2[(size_t)t*256 + j] * sh1[j];
        a = a * (hg2[t] * BNS) + hbb2[t];
        sh2[t] = fmaxf(a, 0.f);
      }
      __syncthreads();
      if (t < CLSn){
        float a = hbi3[t];
        for (int j = 0; j < 256; ++j) a += hw3[(size_t)t*256 + j] * sh2[j];
        outp[wu*CLSn + t] = a;
      }
      __syncthreads();
    }
  }
}

extern "C" void kernel_launch(void* const* d_in, const int* in_sizes, int n_in,
                              void* d_out, int out_size, void* d_ws, size_t ws_size,
                              hipStream_t stream) {
  if (n_in < 42) return;
  if (out_size < Bn*CLSn) return;
  constexpr size_t WS_FLOATS = 3919936;
  if (ws_size < WS_FLOATS * sizeof(float)) return;
  constexpr size_t MIDF = 5812224;
  constexpr size_t BIGF = 9437184;
  const bool mid = ws_size >= (WS_FLOATS + MIDF) * sizeof(float);
  const bool big = ws_size >= (WS_FLOATS + MIDF + BIGF) * sizeof(float);

  const float* pts       = (const float*)d_in[0];
  const float* enc_w1    = (const float*)d_in[1];  const float* enc_b1    = (const float*)d_in[2];
  const float* enc_bn1_g = (const float*)d_in[3];  const float* enc_bn1_b = (const float*)d_in[4];
  const float* enc_w2    = (const float*)d_in[5];  const float* enc_b2    = (const float*)d_in[6];
  const float* enc_w3    = (const float*)d_in[7];  const float* enc_b3    = (const float*)d_in[8];
  const float* enc_bn2_g = (const float*)d_in[9];  const float* enc_bn2_b = (const float*)d_in[10];
  const float* enc_w4    = (const float*)d_in[11]; const float* enc_b4    = (const float*)d_in[12];
  const float* pos_w1    = (const float*)d_in[13]; const float* pos_b1    = (const float*)d_in[14];
  const float* pos_w2    = (const float*)d_in[15]; const float* pos_b2    = (const float*)d_in[16];
  const float* ln_w      = (const float*)d_in[17]; const float* ln_b      = (const float*)d_in[18];
  const float* in_proj_w = (const float*)d_in[19];
  const float* conv_w    = (const float*)d_in[20]; const float* conv_b    = (const float*)d_in[21];
  const float* x_proj_w  = (const float*)d_in[22];
  const float* dt_proj_w = (const float*)d_in[23]; const float* dt_proj_b = (const float*)d_in[24];
  const float* A_log     = (const float*)d_in[25]; const float* D_param   = (const float*)d_in[26];
  const float* out_proj_w= (const float*)d_in[27];
  const float* normf_w   = (const float*)d_in[28]; const float* normf_b   = (const float*)d_in[29];
  const float* norm_w    = (const float*)d_in[30]; const float* norm_b    = (const float*)d_in[31];
  const float* head_w1   = (const float*)d_in[32]; const float* head_b1   = (const float*)d_in[33];
  const float* head_bn1_g= (const float*)d_in[34]; const float* head_bn1_b= (const float*)d_in[35];
  const float* head_w2   = (const float*)d_in[36]; const float* head_b2   = (const float*)d_in[37];
  const float* head_bn2_g= (const float*)d_in[38]; const float* head_bn2_b= (const float*)d_in[39];
  const float* head_w3   = (const float*)d_in[40]; const float* head_b3   = (const float*)d_in[41];

  float* ws = (float*)d_ws;
  float* hb   = ws;
  float* resb = ws + 589824;
  float* U    = ws + 1179648;
  float* center = U;
  float* nb     = U + 1536;
  float* tok    = U + 50688;
  int*   order  = (int*)(U + 247296);
  bf16*  F3b_s  = (bf16*)(U + 262144);
  bf16*  F3c_s  = (bf16*)(U + 1310720);
  float* xz   = U;
  float* xdb  = U + 2359296;
  bf16*  xb   = (bf16*)(U + 2445312);
  float* SBdt_s = U + 2445312;
  float* BND  = U + 2482176;
  float* SBS_sm = hb;
  float* xf   = U;
  float* featp = U + 589824;
  float* WB = ws + WS_FLOATS;
  bf16* wb_ip = (bf16*)WB;
  bf16* wb_op = (bf16*)(WB + 3538944);
  bf16* wb_xp = (bf16*)(WB + 5308416);
  bf16* wb_e2 = (bf16*)(WB + 5566464);
  bf16* wb_e3 = (bf16*)(WB + 5582848);
  bf16* wb_e4 = (bf16*)(WB + 5713920);
  float* BIGB = WB + MIDF;
  bf16*  F3bB = (bf16*)BIGB;
  bf16*  F3cB = (bf16*)(BIGB + 4194304);
  float* xdbp_b = BIGB;
  float* xdbR   = BIGB + 1032192;
  bf16*  yb     = (bf16*)(BIGB + 1118208);
  float* SBS_b  = BIGB + 1708032;
  float* H0b    = BIGB + 4067328;
  float* SBdt_b = BIGB + 6426624;       // ends 6,574,080
  int*   syncp  = (int*)(BIGB + 6600000);

  front_kernel<<<mid ? (Bn + 11352) : Bn, 256, 0, stream>>>(pts, center,
      in_proj_w, out_proj_w, x_proj_w, enc_w2, enc_w3, enc_w4, (bf16*)WB);
  knn_kernel<<<Bn*Gn, 256, 0, stream>>>(pts, center, nb);

  if (big){
    enc2_kernel<bf16><<<dim3(256,2), 256, 0, stream>>>(nb, enc_w1, enc_b1,
        enc_bn1_g, enc_bn1_b, wb_e2, enc_b2, F3bB);
    gemm_mfma128<bf16,bf16,1,bf16,0><<<dim3(256,4), 256, 0, stream>>>(F3bB, 512,
        wb_e3, enc_b3, enc_bn2_g, enc_bn2_b, F3cB, 512, 16384, 512, 512);
    gemm_mfma128<bf16,bf16,0,float,2><<<dim3(256,3), 256, 0, stream>>>(F3cB, 512,
        wb_e4, enc_b4, nullptr, nullptr, (float*)tok, DM, 16384, 384, 512);
  } else {
    for (int b = 0; b < Bn; ++b){
      const float* nbc = nb + (size_t)b*MC*3;
      float* tokc = tok + (size_t)b*Gn*DM;
      if (mid){
        enc2_kernel<bf16><<<dim3(64,2), 256, 0, stream>>>(nbc, enc_w1, enc_b1,
            enc_bn1_g, enc_bn1_b, wb_e2, enc_b2, F3b_s);
        gemm_mfma128<bf16,bf16,1,bf16,0><<<dim3(64,4), 256, 0, stream>>>(F3b_s, 512,
            wb_e3, enc_b3, enc_bn2_g, enc_bn2_b, F3c_s, 512, MC, 512, 512);
        gemm_mfma128<bf16,bf16,0,float,2><<<dim3(64,3), 256, 0, stream>>>(F3c_s, 512,
            wb_e4, enc_b4, nullptr, nullptr, (float*)tokc, DM, MC, 384, 512);
      } else {
        enc2_kernel<float><<<dim3(64,2), 256, 0, stream>>>(nbc, enc_w1, enc_b1,
            enc_bn1_g, enc_bn1_b, enc_w2, enc_b2, F3b_s);
        gemm_mfma128<bf16,float,1,bf16,0><<<dim3(64,4), 256, 0, stream>>>(F3b_s, 512,
            enc_w3, enc_b3, enc_bn2_g, enc_bn2_b, F3c_s, 512, MC, 512, 512);
        gemm_mfma128<bf16,float,0,float,2><<<dim3(64,3), 256, 0, stream>>>(F3c_s, 512,
            enc_w4, enc_b4, nullptr, nullptr, (float*)tokc, DM, MC, 384, 512);
      }
    }
  }

  pos_sort_kernel<<<Bn*Gn + Bn*3, 128, 0, stream>>>(center, pos_w1, pos_b1,
      pos_w2, pos_b2, tok, order);

  if (big){
    hipMemsetAsync(syncp, 0, 16, stream);
    mega_layers<<<MGRID, 256, 0, stream>>>(
        tok, order, hb, resb, xb, xz, xdbp_b, xdbR, yb, SBS_b, SBdt_b, H0b,
        syncp, ln_w, ln_b, wb_ip, wb_xp, wb_op,
        conv_w, conv_b, dt_proj_w, dt_proj_b, A_log, D_param,
        normf_w, normf_b, norm_w, norm_b, xf, featp,
        head_w1, head_b1, head_bn1_g, head_bn1_b,
        head_w2, head_b2, head_bn2_g, head_bn2_b,
        head_w3, head_b3, (float*)d_out);
  } else {
    for (int l = 0; l < DEPTH; ++l){
      const float* lnw  = ln_w      + (size_t)l*DM;
      const float* lnb  = ln_b      + (size_t)l*DM;
      const float* ipw  = in_proj_w + (size_t)l*1536*DM;
      const float* cw   = conv_w    + (size_t)l*DI*4;
      const float* cb   = conv_b    + (size_t)l*DI;
      const float* xpw  = x_proj_w  + (size_t)l*56*DI;
      const float* dpw  = dt_proj_w + (size_t)l*DI*DTR;
      const float* dpb  = dt_proj_b + (size_t)l*DI;
      const float* Alg  = A_log     + (size_t)l*DI*DSt;
      const float* Dpar = D_param   + (size_t)l*DI;
      const float* opw  = out_proj_w+ (size_t)l*DM*DI;

      if (l == 0)
        ln_res_first<<<Bn*Ln/4, 256, 0, stream>>>(tok, order, resb, xb, lnw, lnb);
      else
        ln_res_kernel<<<Bn*Ln/4, 256, 0, stream>>>(hb, resb, xb, lnw, lnb);
      if (mid){
        gemm_mfma128<bf16,bf16,0,float,0><<<dim3(24,12), 256, 0, stream>>>(xb, DM,
            wb_ip + (size_t)l*1536*DM, nullptr, nullptr, nullptr, xz, 1536, Bn*Ln, 1536, DM);
        xproj_kernel<bf16><<<dim3(24,1), 256, 0, stream>>>(xz,
            wb_xp + (size_t)l*56*DI, cw, cb, xdb, DI);
      } else {
        gemm_mfma128<bf16,float,0,float,0><<<dim3(24,12), 256, 0, stream>>>(xb, DM, ipw,
            nullptr, nullptr, nullptr, xz, 1536, Bn*Ln, 1536, DM);
        xproj_kernel<float><<<dim3(24,1), 256, 0, stream>>>(xz, xpw, cw, cb, xdb, DI);
      }
      scanA_kernel<<<Bn*3*NCH, 256, 0, stream>>>(xz, xdb, 1, cw, cb,
          dpw, dpb, Alg, SBS_sm, SBdt_s, BND);
      scanB_kernel<<<Bn*3*NCH, 256, 0, stream>>>(xz, xdb, 1, cw, cb,
          dpw, dpb, Alg, Dpar, SBS_sm, SBdt_s, BND);
      if (mid){
        gemm_mfma64<float,bf16,0,1><<<dim3(24,6), 256, 0, stream>>>(xz, 1536,
            wb_op + (size_t)l*DM*DI, nullptr, xz, nullptr, hb, DM, Bn*Ln, DM, DI);
      } else {
        gemm_mfma64<float,float,0,1><<<dim3(24,6), 256, 0, stream>>>(xz, 1536, opw,
            nullptr, xz, nullptr, hb, DM, Bn*Ln, DM, DI);
      }
    }
    final_ln_kernel<<<Bn*Ln/4, 256, 0, stream>>>(hb, resb, normf_w, normf_b, norm_w, norm_b, xf);
    mean_kernel<<<Bn*4, 384, 0, stream>>>(xf, featp);
    head_mlp<<<Bn, 256, 0, stream>>>(featp, head_w1, head_b1, head_bn1_g, head_bn1_b,
                                     head_w2, head_b2, head_bn2_g, head_bn2_b,
                                     head_w3, head_b3, (float*)d_out);
  }
}

// Round 11
// 1472.629 us; speedup vs baseline: 3.6389x; 3.6389x over previous
//
#include <hip/hip_runtime.h>
#include <hip/hip_bf16.h>

using bf16 = __hip_bfloat16;
using short8  = __attribute__((ext_vector_type(8))) short;
using floatx4 = __attribute__((ext_vector_type(4))) float;
using ull = unsigned long long;

constexpr int Bn = 4, Np = 1024, Gn = 128, Kn = 32;
constexpr int DM = 384, DEPTH = 12, CLSn = 40;
constexpr int DI = 768, DSt = 16, DTR = 24;
constexpr int Ln = 384;
constexpr int NCH = 12, CHS = 32;      // legacy scan (small path)
constexpr int CHB = 8,  NCB = 48;      // big-path scan: 8-step chunks, 576 blocks
constexpr int XDBS = 1536*56;
constexpr int MC = 4096;               // encoder chunk rows (small path)
constexpr float EPSf = 1e-5f;
constexpr float BNS = 0.99999500003749968752f; // 1/sqrt(1+1e-5)
constexpr float LOG2E = 1.4426950408889634f;

static __device__ __forceinline__ short f2bf(float f){
  bf16 h = __float2bfloat16(f);
  return *reinterpret_cast<short*>(&h);
}
static __device__ __forceinline__ float fsig(float x){ return 1.f/(1.f + __expf(-x)); }
static __device__ __forceinline__ float fsoftplus(float x){
  return fmaxf(x, 0.f) + __logf(1.f + __expf(-fabsf(x)));
}
static __device__ __forceinline__ ull umax64(ull a, ull b){ return a > b ? a : b; }

template<int CTRL>
static __device__ __forceinline__ int dppmov(int x){
  return __builtin_amdgcn_update_dpp(0, x, CTRL, 0xF, 0xF, true);
}
static __device__ __forceinline__ ull redmax64(ull key){
  #define RSTEP(CTRL) { \
    int hi = (int)(unsigned)(key >> 32), lo = (int)(unsigned)key; \
    int h2 = dppmov<CTRL>(hi), l2 = dppmov<CTRL>(lo); \
    ull k2 = ((ull)(unsigned)h2 << 32) | (unsigned)l2; \
    if (k2 > key) key = k2; }
  RSTEP(0x111) RSTEP(0x112) RSTEP(0x114) RSTEP(0x118) RSTEP(0x142) RSTEP(0x143)
  #undef RSTEP
  return key;
}

// ---------------------------------------------------------------- front: fps (blocks 0..3) || cvt_all (rest)
__global__ __launch_bounds__(256) void front_kernel(const float* __restrict__ pts,
    float* __restrict__ center,
    const float* __restrict__ s0, const float* __restrict__ s1,
    const float* __restrict__ s2, const float* __restrict__ s3,
    const float* __restrict__ s4, const float* __restrict__ s5,
    bf16* __restrict__ dst){
  __shared__ float4 P[1024];
  __shared__ ull red[2][4];
  if (blockIdx.x >= Bn){
    long i = ((long)(blockIdx.x - Bn)*256 + threadIdx.x)*4;
    if (i >= 11624448L) return;
    const float* s; long off;
    if      (i <  7077888L){ s = s0; off = 0L; }
    else if (i < 10616832L){ s = s1; off =  7077888L; }
    else if (i < 11132928L){ s = s2; off = 10616832L; }
    else if (i < 11165696L){ s = s3; off = 11132928L; }
    else if (i < 11427840L){ s = s4; off = 11165696L; }
    else                   { s = s5; off = 11427840L; }
    float4 v = *(const float4*)(s + (i - off));
    short* o = (short*)dst + i;
    o[0] = f2bf(v.x); o[1] = f2bf(v.y); o[2] = f2bf(v.z); o[3] = f2bf(v.w);
    return;
  }
  int b = blockIdx.x, t = threadIdx.x;
  int w = t >> 6, lane = t & 63;
  const float* p = pts + (size_t)b * Np * 3;
  float X[4], Y[4], Z[4], D[4];
  #pragma unroll
  for (int i = 0; i < 4; ++i){
    int n = t + 256*i;
    float a = p[n*3+0], c = p[n*3+1], e = p[n*3+2];
    X[i] = a; Y[i] = c; Z[i] = e;
    P[n] = make_float4(a, c, e, 0.f);
    D[i] = 1e10f;
  }
  __syncthreads();
  float4 c0 = P[0];
  float px = c0.x, py = c0.y, pz = c0.z;
  if (t == 0){
    center[(size_t)(b*Gn)*3+0] = px;
    center[(size_t)(b*Gn)*3+1] = py;
    center[(size_t)(b*Gn)*3+2] = pz;
  }
  for (int it = 1; it < Gn; ++it){
    float v = -1.f; int nbest = t;
    #pragma unroll
    for (int i = 0; i < 4; ++i){
      float dx = __fsub_rn(X[i], px);
      float dy = __fsub_rn(Y[i], py);
      float dz = __fsub_rn(Z[i], pz);
      float d  = __fadd_rn(__fadd_rn(__fmul_rn(dx,dx), __fmul_rn(dy,dy)), __fmul_rn(dz,dz));
      float dm = fminf(D[i], d); D[i] = dm;
      if (dm > v){ v = dm; nbest = t + 256*i; }
    }
    ull key = ((ull)__float_as_uint(v) << 32) | (unsigned)(Np-1 - nbest);
    key = redmax64(key);
    if (lane == 63) red[it & 1][w] = key;
    __syncthreads();
    ull k = umax64(umax64(red[it & 1][0], red[it & 1][1]),
                   umax64(red[it & 1][2], red[it & 1][3]));
    int wn = Np-1 - (int)(unsigned)(k & 0xFFFFFFFFu);
    wn = min(max(wn, 0), Np-1);
    float4 cc = P[wn];
    px = cc.x; py = cc.y; pz = cc.z;
    if (t == 0){
      center[(size_t)(b*Gn+it)*3+0] = px;
      center[(size_t)(b*Gn+it)*3+1] = py;
      center[(size_t)(b*Gn+it)*3+2] = pz;
    }
  }
}

// ---------------------------------------------------------------- KNN
__global__ __launch_bounds__(256) void knn_kernel(const float* __restrict__ pts,
                                                  const float* __restrict__ center,
                                                  float* __restrict__ nb){
  int gid = blockIdx.x; int b = gid >> 7;
  __shared__ float d2[1024];
  __shared__ float rv[4]; __shared__ int ri[4];
  int t = threadIdx.x;
  float cx = center[(size_t)gid*3+0], cy = center[(size_t)gid*3+1], cz = center[(size_t)gid*3+2];
  const float* p = pts + (size_t)b * Np * 3;
  for (int n = t; n < Np; n += 256){
    float dx = __fsub_rn(cx, p[n*3+0]);
    float dy = __fsub_rn(cy, p[n*3+1]);
    float dz = __fsub_rn(cz, p[n*3+2]);
    d2[n] = __fadd_rn(__fadd_rn(__fmul_rn(dx,dx), __fmul_rn(dy,dy)), __fmul_rn(dz,dz));
  }
  __syncthreads();
  for (int kk = 0; kk < Kn; ++kk){
    float v = 3e38f; int idx = 0;
    for (int n = t; n < Np; n += 256){
      float d = d2[n];
      if (d < v || (d == v && n < idx)){ v = d; idx = n; }
    }
    ull key = ((ull)(unsigned)(~__float_as_uint(v)) << 32) | (unsigned)(Np-1 - idx);
    key = redmax64(key);
    if ((t & 63) == 63){
      rv[t>>6] = __uint_as_float(~(unsigned)(key >> 32));
      ri[t>>6] = Np-1 - (int)(unsigned)(key & 0xFFFFFFFFu);
    }
    __syncthreads();
    if (t == 0){
      float bv = rv[0]; int bi = ri[0];
      for (int w = 1; w < 4; ++w){
        if (rv[w] < bv || (rv[w] == bv && ri[w] < bi)){ bv = rv[w]; bi = ri[w]; }
      }
      bi = min(max(bi, 0), Np-1);
      nb[((size_t)gid*Kn+kk)*3+0] = __fsub_rn(p[bi*3+0], cx);
      nb[((size_t)gid*Kn+kk)*3+1] = __fsub_rn(p[bi*3+1], cy);
      nb[((size_t)gid*Kn+kk)*3+2] = __fsub_rn(p[bi*3+2], cz);
      d2[bi] = 3e38f;
    }
    __syncthreads();
  }
}

// ---------------------------------------------------------------- enc2: fused enc1 (3->128, bn+relu) + GEMM(128->256) + group-max
template<typename WT>
__global__ __launch_bounds__(256) void enc2_kernel(const float* __restrict__ nb,
    const float* __restrict__ w1, const float* __restrict__ b1,
    const float* __restrict__ g1, const float* __restrict__ bb1,
    const WT* __restrict__ W2, const float* __restrict__ b2,
    bf16* __restrict__ F3b){
  __shared__ __align__(16) short As[64*72];
  __shared__ __align__(16) short Ws[128*72];
  __shared__ float w1s0[128], w1s1[128], w1s2[128], sa[128], sc[128];
  int bm = blockIdx.x * 64, bn = blockIdx.y * 128;
  int t = threadIdx.x;
  int row = t >> 2, kseg = (t & 3) * 16;
  int row2 = t >> 1, kseg2 = (t & 1) * 32;
  int w = t >> 6, lane = t & 63, m16 = lane & 15, q = lane >> 4;
  if (t < 128){
    float a = g1[t] * BNS;
    w1s0[t] = w1[t*3+0]; w1s1[t] = w1[t*3+1]; w1s2[t] = w1[t*3+2];
    sa[t] = a; sc[t] = b1[t]*a + bb1[t];
  }
  const float* nbr = nb + (size_t)(bm + row)*3;
  float p0 = nbr[0], p1 = nbr[1], p2 = nbr[2];
  __syncthreads();
  floatx4 acc[8] = {};
  for (int k0 = 0; k0 < 128; k0 += 64){
    {
      short* dstp = &As[row*72 + kseg];
      #pragma unroll
      for (int j = 0; j < 16; ++j){
        int c = k0 + kseg + j;
        float v = p0*w1s0[c] + p1*w1s1[c] + p2*w1s2[c];
        v = fmaxf(v*sa[c] + sc[c], 0.f);
        dstp[j] = f2bf(v);
      }
    }
    {
      int n = bn + row2;
      if constexpr (sizeof(WT) == 2){
        const short* Wr = (const short*)W2 + (size_t)n*128 + k0 + kseg2;
        *(short8*)&Ws[row2*72 + kseg2]      = *(const short8*)Wr;
        *(short8*)&Ws[row2*72 + kseg2 + 8]  = *(const short8*)(Wr + 8);
        *(short8*)&Ws[row2*72 + kseg2 + 16] = *(const short8*)(Wr + 16);
        *(short8*)&Ws[row2*72 + kseg2 + 24] = *(const short8*)(Wr + 24);
      } else {
        const float* Wr = (const float*)W2 + (size_t)n*128 + k0 + kseg2;
        float wv[32];
        #pragma unroll
        for (int j = 0; j < 8; ++j) *(float4*)&wv[j*4] = *(const float4*)(Wr + j*4);
        short* dstp = &Ws[row2*72 + kseg2];
        #pragma unroll
        for (int jj = 0; jj < 32; ++jj) dstp[jj] = f2bf(wv[jj]);
      }
    }
    __syncthreads();
    short8 af0 = *(const short8*)&As[(w*16 + m16)*72 + q*8];
    short8 af1 = *(const short8*)&As[(w*16 + m16)*72 + 32 + q*8];
    #pragma unroll
    for (int j = 0; j < 8; ++j){
      short8 b0 = *(const short8*)&Ws[(j*16 + m16)*72 + q*8];
      acc[j] = __builtin_amdgcn_mfma_f32_16x16x32_bf16(af0, b0, acc[j], 0, 0, 0);
      short8 b1v = *(const short8*)&Ws[(j*16 + m16)*72 + 32 + q*8];
      acc[j] = __builtin_amdgcn_mfma_f32_16x16x32_bf16(af1, b1v, acc[j], 0, 0, 0);
    }
    __syncthreads();
  }
  float val[8][4];
  #pragma unroll
  for (int j = 0; j < 8; ++j){
    int n = bn + j*16 + m16;
    float bv = b2[n];
    #pragma unroll
    for (int r = 0; r < 4; ++r) val[j][r] = acc[j][r] + bv;
  }
  float* mat = (float*)As;
  #pragma unroll
  for (int j = 0; j < 8; ++j){
    float lm = fmaxf(fmaxf(val[j][0], val[j][1]), fmaxf(val[j][2], val[j][3]));
    mat[(w*4 + q)*128 + j*16 + m16] = lm;
  }
  bf16* C = F3b + 256;
  #pragma unroll
  for (int j = 0; j < 8; ++j){
    int n = bn + j*16 + m16;
    #pragma unroll
    for (int r = 0; r < 4; ++r){
      int m = bm + w*16 + q*4 + r;
      C[(size_t)m*512 + n] = __float2bfloat16(val[j][r]);
    }
  }
  __syncthreads();
  int col = t & 127, half = t >> 7;
  float gm = mat[(half*8)*128 + col];
  #pragma unroll
  for (int s = 1; s < 8; ++s) gm = fmaxf(gm, mat[(half*8 + s)*128 + col]);
  bf16 gb = __float2bfloat16(gm);      // exact: round(max)=max(round)
  bf16* dstm = F3b + (size_t)(bm + half*32)*512 + bn + col;
  #pragma unroll
  for (int rr = 0; rr < 32; ++rr) dstm[(size_t)rr*512] = gb;
}

// ---------------------------------------------------------------- MFMA GEMM 64x128, BK=64
// POOL=0: plain write. POOL=2: write ONLY per-32-row group col-max to C.
template<typename AT, typename WT, int ACT, typename CT, int POOL>
__global__ __launch_bounds__(256) void gemm_mfma128(const AT* __restrict__ A, int lda,
                                                    const WT* __restrict__ W,
                                                    const float* __restrict__ bias,
                                                    const float* __restrict__ gz,
                                                    const float* __restrict__ bbp,
                                                    CT* __restrict__ C, int ldc,
                                                    int M, int N, int K){
  __shared__ __align__(16) short As[64*72];
  __shared__ __align__(16) short Ws[128*72];
  int bm = blockIdx.x * 64, bn = blockIdx.y * 128;
  int t = threadIdx.x;
  int row = t >> 2, kseg = (t & 3) * 16;
  int row2 = t >> 1, kseg2 = (t & 1) * 32;
  int w = t >> 6, lane = t & 63, m16 = lane & 15, q = lane >> 4;
  floatx4 acc[8] = {};
  for (int k0 = 0; k0 < K; k0 += 64){
    if constexpr (sizeof(AT) == 2){
      const short* Ar = (const short*)A + (size_t)(bm + row)*lda + k0 + kseg;
      *(short8*)&As[row*72 + kseg]     = *(const short8*)Ar;
      *(short8*)&As[row*72 + kseg + 8] = *(const short8*)(Ar + 8);
    } else {
      const float* Ar = (const float*)A + (size_t)(bm + row)*lda + k0 + kseg;
      float a[16];
      #pragma unroll
      for (int j = 0; j < 4; ++j) *(float4*)&a[j*4] = *(const float4*)(Ar + j*4);
      short* dstp = &As[row*72 + kseg];
      #pragma unroll
      for (int jj = 0; jj < 16; ++jj) dstp[jj] = f2bf(a[jj]);
    }
    {
      int n = bn + row2;
      if constexpr (sizeof(WT) == 2){
        short8 v0, v1, v2, v3;
        #pragma unroll
        for (int j = 0; j < 8; ++j){ v0[j] = 0; v1[j] = 0; v2[j] = 0; v3[j] = 0; }
        if (n < N){
          const short* Wr = (const short*)W + (size_t)n*K + k0 + kseg2;
          v0 = *(const short8*)Wr;
          v1 = *(const short8*)(Wr + 8);
          v2 = *(const short8*)(Wr + 16);
          v3 = *(const short8*)(Wr + 24);
        }
        *(short8*)&Ws[row2*72 + kseg2]      = v0;
        *(short8*)&Ws[row2*72 + kseg2 + 8]  = v1;
        *(short8*)&Ws[row2*72 + kseg2 + 16] = v2;
        *(short8*)&Ws[row2*72 + kseg2 + 24] = v3;
      } else {
        short* dstp = &Ws[row2*72 + kseg2];
        if (n < N){
          const float* Wr = (const float*)W + (size_t)n*K + k0 + kseg2;
          float wv[32];
          #pragma unroll
          for (int j = 0; j < 8; ++j) *(float4*)&wv[j*4] = *(const float4*)(Wr + j*4);
          #pragma unroll
          for (int jj = 0; jj < 32; ++jj) dstp[jj] = f2bf(wv[jj]);
        } else {
          #pragma unroll
          for (int jj = 0; jj < 32; ++jj) dstp[jj] = 0;
        }
      }
    }
    __syncthreads();
    short8 af0 = *(const short8*)&As[(w*16 + m16)*72 + q*8];
    short8 af1 = *(const short8*)&As[(w*16 + m16)*72 + 32 + q*8];
    #pragma unroll
    for (int j = 0; j < 8; ++j){
      short8 b0 = *(const short8*)&Ws[(j*16 + m16)*72 + q*8];
      acc[j] = __builtin_amdgcn_mfma_f32_16x16x32_bf16(af0, b0, acc[j], 0, 0, 0);
      short8 b1 = *(const short8*)&Ws[(j*16 + m16)*72 + 32 + q*8];
      acc[j] = __builtin_amdgcn_mfma_f32_16x16x32_bf16(af1, b1, acc[j], 0, 0, 0);
    }
    __syncthreads();
  }
  float val[8][4];
  #pragma unroll
  for (int j = 0; j < 8; ++j){
    int n = bn + j*16 + m16;
    float bv = (bias && n < N) ? bias[n] : 0.f;
    float gv = 0.f, bbv = 0.f;
    if (ACT == 1 && n < N){ gv = gz[n] * BNS; bbv = bbp[n]; }
    #pragma unroll
    for (int r = 0; r < 4; ++r){
      float v = acc[j][r] + bv;
      if (ACT == 1){ v = v * gv + bbv; v = fmaxf(v, 0.f); }
      val[j][r] = v;
    }
  }
  if constexpr (POOL == 0){
    #pragma unroll
    for (int j = 0; j < 8; ++j){
      int n = bn + j*16 + m16;
      if (n < N){
        #pragma unroll
        for (int r = 0; r < 4; ++r){
          int m = bm + w*16 + q*4 + r;
          if constexpr (sizeof(CT) == 2) C[(size_t)m*ldc + n] = __float2bfloat16(val[j][r]);
          else                           C[(size_t)m*ldc + n] = val[j][r];
        }
      }
    }
  } else {
    float* mat = (float*)As;
    #pragma unroll
    for (int j = 0; j < 8; ++j){
      float lm = fmaxf(fmaxf(val[j][0], val[j][1]), fmaxf(val[j][2], val[j][3]));
      mat[(w*4 + q)*128 + j*16 + m16] = lm;
    }
    __syncthreads();
    int col = t & 127, half = t >> 7;
    float gm = mat[(half*8)*128 + col];
    #pragma unroll
    for (int s = 1; s < 8; ++s) gm = fmaxf(gm, mat[(half*8 + s)*128 + col]);
    int g = (bm >> 5) + half;
    ((float*)C)[(size_t)g*ldc + bn + col] = gm;
  }
}

// ---------------------------------------------------------------- MFMA GEMM 64x64, BK=64 (small-path out_proj MODE1)
template<typename AT, typename WT, int ACT, int MODE, typename CT = float>
__global__ __launch_bounds__(256) void gemm_mfma64(const AT* __restrict__ A, int lda,
                                                   const WT* __restrict__ W,
                                                   const float* __restrict__ bias,
                                                   const float* __restrict__ gz,
                                                   const float* __restrict__ bbp,
                                                   CT* __restrict__ C, int ldc,
                                                   int M, int N, int K){
  __shared__ __align__(16) short As[64*72];
  __shared__ __align__(16) short Ws[64*72];
  int bm = blockIdx.x * 64, bn = blockIdx.y * 64;
  int t = threadIdx.x;
  int row = t >> 2, kseg = (t & 3) * 16;
  int w = t >> 6, lane = t & 63, m16 = lane & 15, q = lane >> 4;
  floatx4 acc[4] = {};
  for (int k0 = 0; k0 < K; k0 += 64){
    if constexpr (MODE == 1){
      const float* Yr = (const float*)A + (size_t)(bm + row)*lda + k0 + kseg;
      const float* Zr = gz + (size_t)(bm + row)*1536 + 768 + k0 + kseg;
      float y[16], z[16];
      #pragma unroll
      for (int j = 0; j < 4; ++j){
        *(float4*)&y[j*4] = *(const float4*)(Yr + j*4);
        *(float4*)&z[j*4] = *(const float4*)(Zr + j*4);
      }
      short* dstp = &As[row*72 + kseg];
      #pragma unroll
      for (int jj = 0; jj < 16; ++jj) dstp[jj] = f2bf(y[jj] * (z[jj] * fsig(z[jj])));
    } else if constexpr (sizeof(AT) == 2){
      const short* Ar = (const short*)A + (size_t)(bm + row)*lda + k0 + kseg;
      *(short8*)&As[row*72 + kseg]     = *(const short8*)Ar;
      *(short8*)&As[row*72 + kseg + 8] = *(const short8*)(Ar + 8);
    } else {
      const float* Ar = (const float*)A + (size_t)(bm + row)*lda + k0 + kseg;
      float a[16];
      #pragma unroll
      for (int j = 0; j < 4; ++j) *(float4*)&a[j*4] = *(const float4*)(Ar + j*4);
      short* dstp = &As[row*72 + kseg];
      #pragma unroll
      for (int jj = 0; jj < 16; ++jj) dstp[jj] = f2bf(a[jj]);
    }
    {
      int n = bn + row;
      if constexpr (sizeof(WT) == 2){
        short8 v0, v1;
        #pragma unroll
        for (int j = 0; j < 8; ++j){ v0[j] = 0; v1[j] = 0; }
        if (n < N){
          const short* Wr = (const short*)W + (size_t)n*K + k0 + kseg;
          v0 = *(const short8*)Wr;
          v1 = *(const short8*)(Wr + 8);
        }
        *(short8*)&Ws[row*72 + kseg]     = v0;
        *(short8*)&Ws[row*72 + kseg + 8] = v1;
      } else {
        short* dstp = &Ws[row*72 + kseg];
        if (n < N){
          const float* Wr = (const float*)W + (size_t)n*K + k0 + kseg;
          float wv[16];
          #pragma unroll
          for (int j = 0; j < 4; ++j) *(float4*)&wv[j*4] = *(const float4*)(Wr + j*4);
          #pragma unroll
          for (int jj = 0; jj < 16; ++jj) dstp[jj] = f2bf(wv[jj]);
        } else {
          #pragma unroll
          for (int jj = 0; jj < 16; ++jj) dstp[jj] = 0;
        }
      }
    }
    __syncthreads();
    short8 af0 = *(const short8*)&As[(w*16 + m16)*72 + q*8];
    short8 af1 = *(const short8*)&As[(w*16 + m16)*72 + 32 + q*8];
    #pragma unroll
    for (int j = 0; j < 4; ++j){
      short8 b0 = *(const short8*)&Ws[(j*16 + m16)*72 + q*8];
      acc[j] = __builtin_amdgcn_mfma_f32_16x16x32_bf16(af0, b0, acc[j], 0, 0, 0);
      short8 b1 = *(const short8*)&Ws[(j*16 + m16)*72 + 32 + q*8];
      acc[j] = __builtin_amdgcn_mfma_f32_16x16x32_bf16(af1, b1, acc[j], 0, 0, 0);
    }
    __syncthreads();
  }
  #pragma unroll
  for (int j = 0; j < 4; ++j){
    int n = bn + j*16 + m16;
    if (n < N){
      float bv = bias ? bias[n] : 0.f;
      #pragma unroll
      for (int r = 0; r < 4; ++r){
        int m = bm + w*16 + q*4 + r;
        float v = acc[j][r] + bv;
        if constexpr (sizeof(CT) == 2) C[(size_t)m*ldc + n] = __float2bfloat16(v);
        else                           C[(size_t)m*ldc + n] = v;
      }
    }
  }
}

// ---------------------------------------------------------------- x_proj GEMM with fused causal conv+silu on A (split-K)
template<typename WT>
__global__ __launch_bounds__(256) void xproj_kernel(const float* __restrict__ xz,
                                                    const WT* __restrict__ W,
                                                    const float* __restrict__ cw,
                                                    const float* __restrict__ cb,
                                                    float* __restrict__ xdbp,
                                                    int KB){
  __shared__ __align__(16) short As[64*72];
  __shared__ __align__(16) short Ws[64*72];
  int bm = blockIdx.x * 64;
  int ks = blockIdx.y;
  int t = threadIdx.x;
  int row = t >> 2, kseg = (t & 3) * 16;
  int w = t >> 6, lane = t & 63, m16 = lane & 15, q = lane >> 4;
  int m = bm + row;
  int l = m % Ln;
  const int kbase = ks * KB;
  floatx4 acc[4] = {};
  const float4 z4 = make_float4(0.f, 0.f, 0.f, 0.f);
  for (int k0 = kbase; k0 < kbase + KB; k0 += 64){
    {
      int ch = k0 + kseg;
      const float* base = xz + (size_t)m*1536 + ch;
      float x0[16], x1[16], x2[16], x3[16];
      #pragma unroll
      for (int j4 = 0; j4 < 4; ++j4){
        *(float4*)&x3[j4*4] = *(const float4*)(base + j4*4);
        *(float4*)&x2[j4*4] = (l >= 1) ? *(const float4*)(base - 1536 + j4*4) : z4;
        *(float4*)&x1[j4*4] = (l >= 2) ? *(const float4*)(base - 2*1536 + j4*4) : z4;
        *(float4*)&x0[j4*4] = (l >= 3) ? *(const float4*)(base - 3*1536 + j4*4) : z4;
      }
      short* dstp = &As[row*72 + kseg];
      #pragma unroll
      for (int j = 0; j < 16; ++j){
        float4 wv = *(const float4*)(cw + (size_t)(ch + j)*4);
        float v = x0[j]*wv.x + x1[j]*wv.y + x2[j]*wv.z + x3[j]*wv.w + cb[ch + j];
        v = v * fsig(v);
        dstp[j] = f2bf(v);
      }
    }
    {
      int n = row;
      if constexpr (sizeof(WT) == 2){
        short8 v0, v1;
        #pragma unroll
        for (int j = 0; j < 8; ++j){ v0[j] = 0; v1[j] = 0; }
        if (n < 56){
          const short* Wr = (const short*)W + (size_t)n*DI + k0 + kseg;
          v0 = *(const short8*)Wr;
          v1 = *(const short8*)(Wr + 8);
        }
        *(short8*)&Ws[row*72 + kseg]     = v0;
        *(short8*)&Ws[row*72 + kseg + 8] = v1;
      } else {
        short* dstp = &Ws[row*72 + kseg];
        if (n < 56){
          const float* Wr = (const float*)W + (size_t)n*DI + k0 + kseg;
          float wv[16];
          #pragma unroll
          for (int j = 0; j < 4; ++j) *(float4*)&wv[j*4] = *(const float4*)(Wr + j*4);
          #pragma unroll
          for (int jj = 0; jj < 16; ++jj) dstp[jj] = f2bf(wv[jj]);
        } else {
          #pragma unroll
          for (int jj = 0; jj < 16; ++jj) dstp[jj] = 0;
        }
      }
    }
    __syncthreads();
    short8 af0 = *(const short8*)&As[(w*16 + m16)*72 + q*8];
    short8 af1 = *(const short8*)&As[(w*16 + m16)*72 + 32 + q*8];
    #pragma unroll
    for (int j = 0; j < 4; ++j){
      short8 b0 = *(const short8*)&Ws[(j*16 + m16)*72 + q*8];
      acc[j] = __builtin_amdgcn_mfma_f32_16x16x32_bf16(af0, b0, acc[j], 0, 0, 0);
      short8 b1 = *(const short8*)&Ws[(j*16 + m16)*72 + 32 + q*8];
      acc[j] = __builtin_amdgcn_mfma_f32_16x16x32_bf16(af1, b1, acc[j], 0, 0, 0);
    }
    __syncthreads();
  }
  float* C = xdbp + (size_t)ks * XDBS;
  #pragma unroll
  for (int j = 0; j < 4; ++j){
    int n = j*16 + m16;
    if (n < 56){
      #pragma unroll
      for (int r = 0; r < 4; ++r){
        int mm = bm + w*16 + q*4 + r;
        C[(size_t)mm*56 + n] = acc[j][r];
      }
    }
  }
}

// -------------------------------------------------- pos (blocks 0..511) || sort (512..523)
__global__ __launch_bounds__(128) void pos_sort_kernel(const float* __restrict__ center,
    const float* __restrict__ w1, const float* __restrict__ b1,
    const float* __restrict__ w2, const float* __restrict__ b2,
    float* __restrict__ tok, int* __restrict__ order){
  __shared__ float h1[128]; __shared__ float c3[3];
  __shared__ float key[128];
  int t = threadIdx.x;
  if (blockIdx.x < Bn*Gn){
    int gid = blockIdx.x;
    if (t < 3) c3[t] = center[(size_t)gid*3 + t];
    __syncthreads();
    float a = w1[t*3+0]*c3[0] + w1[t*3+1]*c3[1] + w1[t*3+2]*c3[2] + b1[t];
    h1[t] = 0.5f * a * (1.f + erff(a * 0.70710678118654752440f));
    __syncthreads();
    for (int c = t; c < DM; c += 128){
      float s = b2[c];
      for (int j = 0; j < 128; ++j) s += w2[(size_t)c*128 + j] * h1[j];
      tok[(size_t)gid*DM + c] += s;
    }
  } else {
    int bax = blockIdx.x - Bn*Gn; int b = bax / 3, ax = bax % 3;
    key[t] = center[(size_t)(b*Gn + t)*3 + ax];
    __syncthreads();
    float kt = key[t]; int r = 0;
    for (int j = 0; j < Gn; ++j){
      float kj = key[j];
      r += (kj < kt || (kj == kt && j < t)) ? 1 : 0;
    }
    r = min(max(r, 0), Gn-1);
    order[b*Ln + ax*Gn + r] = t;
  }
}

// -------------------------------------------------- layer-0: gather tok -> res init + LN
__global__ __launch_bounds__(256) void ln_res_first(const float* __restrict__ tok,
                                                    const int* __restrict__ order,
                                                    float* __restrict__ res,
                                                    bf16* __restrict__ x,
                                                    const float* __restrict__ w,
                                                    const float* __restrict__ bias){
  int wv = threadIdx.x >> 6, ln = threadIdx.x & 63;
  int tokid = blockIdx.x*4 + wv;
  int b = tokid / Ln;
  int src = order[tokid];
  src = min(max(src, 0), Gn-1);
  const float* hr = tok + ((size_t)(b*Gn + src))*DM;
  float* rr = res + (size_t)tokid*DM;
  bf16* xr = x + (size_t)tokid*DM;
  float v[6]; float s = 0.f;
  #pragma unroll
  for (int i = 0; i < 6; ++i){ int c = ln + 64*i; float t = hr[c]; rr[c] = t; v[i] = t; s += t; }
  #pragma unroll
  for (int o = 32; o > 0; o >>= 1) s += __shfl_xor(s, o);
  float mu = s * (1.f/DM);
  float q = 0.f;
  #pragma unroll
  for (int i = 0; i < 6; ++i){ float d = v[i] - mu; q += d*d; }
  #pragma unroll
  for (int o = 32; o > 0; o >>= 1) q += __shfl_xor(q, o);
  float rstd = rsqrtf(q * (1.f/DM) + EPSf);
  #pragma unroll
  for (int i = 0; i < 6; ++i){ int c = ln + 64*i;
    xr[c] = __float2bfloat16((v[i]-mu)*rstd*w[c] + bias[c]); }
}

// -------------------------------------------------- res += h; x = LN(res)*w+b (bf16 out)
__global__ __launch_bounds__(256) void ln_res_kernel(const float* __restrict__ h,
                                                     float* __restrict__ res,
                                                     bf16* __restrict__ x,
                                                     const float* __restrict__ w,
                                                     const float* __restrict__ bias){
  int wv = threadIdx.x >> 6, ln = threadIdx.x & 63;
  int tokid = blockIdx.x*4 + wv;
  const float* hr = h + (size_t)tokid*DM;
  float* rr = res + (size_t)tokid*DM;
  bf16* xr = x + (size_t)tokid*DM;
  float v[6]; float s = 0.f;
  #pragma unroll
  for (int i = 0; i < 6; ++i){ int c = ln + 64*i; float t = hr[c] + rr[c]; rr[c] = t; v[i] = t; s += t; }
  #pragma unroll
  for (int o = 32; o > 0; o >>= 1) s += __shfl_xor(s, o);
  float mu = s * (1.f/DM);
  float q = 0.f;
  #pragma unroll
  for (int i = 0; i < 6; ++i){ float d = v[i] - mu; q += d*d; }
  #pragma unroll
  for (int o = 32; o > 0; o >>= 1) q += __shfl_xor(q, o);
  float rstd = rsqrtf(q * (1.f/DM) + EPSf);
  #pragma unroll
  for (int i = 0; i < 6; ++i){ int c = ln + 64*i;
    xr[c] = __float2bfloat16((v[i]-mu)*rstd*w[c] + bias[c]); }
}

// ================================================== BIG-PATH SCAN (CHB=8, NCB=48, 576 blocks)
__global__ __launch_bounds__(256) void scanA_big(const float* __restrict__ xz,
    const float* __restrict__ xdbp, int nks,
    const float* __restrict__ cw, const float* __restrict__ cb,
    const float* __restrict__ dpw, const float* __restrict__ dpb,
    const float* __restrict__ A_log,
    float* __restrict__ SB_S, float* __restrict__ SB_dt,
    float* __restrict__ xdbR){
  __shared__ float sRow[CHB*56];
  int blk = blockIdx.x;
  int c = blk % NCB; int bd = blk / NCB; int dch = bd % 3; int b = bd / 3;
  int t = threadIdx.x; int d = dch*256 + t;
  int l0 = c*CHB;
  for (int i = t; i < CHB*56; i += 256){
    size_t base = ((size_t)(b*Ln + l0))*56 + i;
    float s = xdbp[base];
    for (int k = 1; k < nks; ++k) s += xdbp[(size_t)k*XDBS + base];
    sRow[i] = s;
    if (dch == 0) xdbR[base] = s;
  }
  float xv[CHB+3];
  #pragma unroll
  for (int j = 0; j < 3; ++j){
    int ll = l0 - 3 + j;
    xv[j] = (ll >= 0) ? xz[((size_t)(b*Ln + ll))*1536 + d] : 0.f;
  }
  const float* xp = xz + ((size_t)(b*Ln + l0))*1536 + d;
  #pragma unroll
  for (int i = 0; i < CHB; ++i) xv[3+i] = xp[(size_t)i*1536];
  float cw0 = cw[d*4+0], cw1 = cw[d*4+1], cw2 = cw[d*4+2], cw3 = cw[d*4+3];
  float cbv = cb[d];
  float uu[CHB];
  #pragma unroll
  for (int i = 0; i < CHB; ++i){
    float v = xv[i]*cw0 + xv[i+1]*cw1 + xv[i+2]*cw2 + xv[i+3]*cw3 + cbv;
    uu[i] = v * fsig(v);
  }
  float w[DTR];
  const float* wp = dpw + (size_t)d*DTR;
  #pragma unroll
  for (int j = 0; j < DTR; ++j) w[j] = wp[j];
  float a2[DSt], h[DSt];
  const float* ap = A_log + (size_t)d*DSt;
  #pragma unroll
  for (int s = 0; s < DSt; ++s){ a2[s] = -__expf(ap[s]) * LOG2E; h[s] = 0.f; }
  float dbias = dpb[d];
  float sumdt = 0.f;
  __syncthreads();
  for (int i = 0; i < CHB; ++i){
    int ro = i*56;
    float dtr = dbias;
    #pragma unroll
    for (int j = 0; j < DTR; ++j) dtr += w[j] * sRow[ro + j];
    float dtv = fsoftplus(dtr);
    sumdt += dtv;
    float du = dtv * uu[i];
    #pragma unroll
    for (int s = 0; s < DSt; ++s)
      h[s] = exp2f(dtv * a2[s]) * h[s] + du * sRow[ro + 24 + s];
  }
  size_t sb = ((size_t)blk*256 + t)*16;
  #pragma unroll
  for (int s = 0; s < DSt; ++s) SB_S[sb + s] = h[s];
  SB_dt[(size_t)blk*256 + t] = sumdt;
}

// prefix: one thread per (channel d, state s) — 192 blocks x 256 threads = 49152
// independent 48-step scans. Identical arithmetic/order per (d,s) as before.
__global__ __launch_bounds__(256) void prefix_kernel(const float* __restrict__ A_log,
    const float* __restrict__ SB_S, const float* __restrict__ SB_dt,
    float* __restrict__ H0){
  int bb = blockIdx.x;                  // Bn*3*16
  int bd = bb >> 4;                     // 0..11
  int dch = bd % 3;
  int tt = threadIdx.x;
  int tloc = tt >> 4, s = tt & 15;
  int t = (bb & 15)*16 + tloc;          // 0..255
  int d = dch*256 + t;
  float a2 = -__expf(A_log[(size_t)d*DSt + s]) * LOG2E;
  float H = 0.f;
  size_t tb = ((size_t)bd*NCB)*256 + t;
  for (int c = 0; c < NCB; ++c){
    size_t base = (tb + (size_t)c*256)*16 + s;
    H0[base] = H;
    float sd = SB_dt[tb + (size_t)c*256];
    H = exp2f(sd * a2) * H + SB_S[base];
  }
}

// scanB_big: reads H0 + reduced xdb; writes gated bf16 y*silu(z) to yb (xz untouched)
__global__ __launch_bounds__(256) void scanB_big(const float* __restrict__ xz,
    const float* __restrict__ xdbR,
    const float* __restrict__ cw, const float* __restrict__ cb,
    const float* __restrict__ dpw, const float* __restrict__ dpb,
    const float* __restrict__ A_log, const float* __restrict__ Dp,
    const float* __restrict__ H0, bf16* __restrict__ yb){
  __shared__ float sRow[CHB*56];
  int blk = blockIdx.x;
  int c = blk % NCB; int bd = blk / NCB; int dch = bd % 3; int b = bd / 3;
  int t = threadIdx.x; int d = dch*256 + t;
  int l0 = c*CHB;
  for (int i = t; i < CHB*56; i += 256)
    sRow[i] = xdbR[((size_t)(b*Ln + l0))*56 + i];
  float xv[CHB+3];
  #pragma unroll
  for (int j = 0; j < 3; ++j){
    int ll = l0 - 3 + j;
    xv[j] = (ll >= 0) ? xz[((size_t)(b*Ln + ll))*1536 + d] : 0.f;
  }
  const float* xp = xz + ((size_t)(b*Ln + l0))*1536 + d;
  #pragma unroll
  for (int i = 0; i < CHB; ++i) xv[3+i] = xp[(size_t)i*1536];
  float cw0 = cw[d*4+0], cw1 = cw[d*4+1], cw2 = cw[d*4+2], cw3 = cw[d*4+3];
  float cbv = cb[d];
  float uu[CHB];
  #pragma unroll
  for (int i = 0; i < CHB; ++i){
    float v = xv[i]*cw0 + xv[i+1]*cw1 + xv[i+2]*cw2 + xv[i+3]*cw3 + cbv;
    uu[i] = v * fsig(v);
  }
  float w[DTR];
  const float* wp = dpw + (size_t)d*DTR;
  #pragma unroll
  for (int j = 0; j < DTR; ++j) w[j] = wp[j];
  float a2[DSt], h[DSt];
  const float* ap = A_log + (size_t)d*DSt;
  #pragma unroll
  for (int s = 0; s < DSt; ++s) a2[s] = -__expf(ap[s]) * LOG2E;
  size_t hbase = (((size_t)bd*NCB + c)*256 + t)*16;
  #pragma unroll
  for (int s = 0; s < DSt; ++s) h[s] = H0[hbase + s];
  float dbias = dpb[d];
  float Dd = Dp[d];
  const float* zrow = xz + ((size_t)(b*Ln + l0))*1536 + 768 + d;
  bf16* ybr = yb + ((size_t)(b*Ln + l0))*DI + d;
  __syncthreads();
  for (int i = 0; i < CHB; ++i){
    int ro = i*56;
    float dtr = dbias;
    #pragma unroll
    for (int j = 0; j < DTR; ++j) dtr += w[j] * sRow[ro + j];
    float dtv = fsoftplus(dtr);
    float u = uu[i];
    float du = dtv * u;
    float yv = 0.f;
    #pragma unroll
    for (int s = 0; s < DSt; ++s){
      h[s] = exp2f(dtv * a2[s]) * h[s] + du * sRow[ro + 24 + s];
      yv += h[s] * sRow[ro + 40 + s];
    }
    float yfull = yv + u*Dd;
    float zv = zrow[(size_t)i*1536];
    ybr[(size_t)i*DI] = __float2bfloat16(yfull * (zv * fsig(zv)));
  }
}

// ================================================== LEGACY SCAN (small/mid path, CHS=32, NCH=12)
__global__ __launch_bounds__(256) void scanA_kernel(const float* __restrict__ xz,
                                                    const float* __restrict__ xdbp, int nks,
                                                    const float* __restrict__ cw,
                                                    const float* __restrict__ cb,
                                                    const float* __restrict__ dpw,
                                                    const float* __restrict__ dpb,
                                                    const float* __restrict__ A_log,
                                                    float* __restrict__ SB_S,
                                                    float* __restrict__ SB_dt,
                                                    float* __restrict__ BND){
  __shared__ float sRow[CHS*56];
  __shared__ float sU[CHS*256];
  int blk = blockIdx.x;
  int c = blk % NCH; int bd = blk / NCH; int dch = bd % 3; int b = bd / 3;
  int t = threadIdx.x; int d = dch*256 + t;
  int l0 = c*CHS;
  for (int i = t; i < CHS*56; i += 256){
    size_t base = ((size_t)(b*Ln + l0))*56 + i;
    float s = xdbp[base];
    for (int k = 1; k < nks; ++k) s += xdbp[(size_t)k*XDBS + base];
    sRow[i] = s;
  }
  float xv[CHS+3];
  #pragma unroll
  for (int j = 0; j < 3; ++j){
    int ll = l0 - 3 + j;
    xv[j] = (ll >= 0) ? xz[((size_t)(b*Ln + ll))*1536 + d] : 0.f;
  }
  const float* xp = xz + ((size_t)(b*Ln + l0))*1536 + d;
  #pragma unroll
  for (int i = 0; i < CHS; ++i) xv[3+i] = xp[(size_t)i*1536];
  #pragma unroll
  for (int j = 0; j < 3; ++j) BND[((size_t)blk*3 + j)*256 + t] = xv[j];
  float cw0 = cw[d*4+0], cw1 = cw[d*4+1], cw2 = cw[d*4+2], cw3 = cw[d*4+3];
  float cbv = cb[d];
  #pragma unroll
  for (int i = 0; i < CHS; ++i){
    float v = xv[i]*cw0 + xv[i+1]*cw1 + xv[i+2]*cw2 + xv[i+3]*cw3 + cbv;
    sU[i*256 + t] = v * fsig(v);
  }
  float w[DTR];
  const float* wp = dpw + (size_t)d*DTR;
  #pragma unroll
  for (int j = 0; j < DTR; ++j) w[j] = wp[j];
  float a2[DSt], h[DSt];
  const float* ap = A_log + (size_t)d*DSt;
  #pragma unroll
  for (int s = 0; s < DSt; ++s){ a2[s] = -__expf(ap[s]) * LOG2E; h[s] = 0.f; }
  float dbias = dpb[d];
  float sumdt = 0.f;
  __syncthreads();
  for (int i = 0; i < CHS; ++i){
    int ro = i*56;
    float dtr = dbias;
    #pragma unroll
    for (int j = 0; j < DTR; ++j) dtr += w[j] * sRow[ro + j];
    float dtv = fsoftplus(dtr);
    sumdt += dtv;
    float du = dtv * sU[i*256 + t];
    #pragma unroll
    for (int s = 0; s < DSt; ++s)
      h[s] = exp2f(dtv * a2[s]) * h[s] + du * sRow[ro + 24 + s];
  }
  size_t sb = ((size_t)blk*256 + t)*16;
  #pragma unroll
  for (int s = 0; s < DSt; ++s) SB_S[sb + s] = h[s];
  SB_dt[(size_t)blk*256 + t] = sumdt;
}

__global__ __launch_bounds__(256) void scanB_kernel(float* __restrict__ xz,
                                                    const float* __restrict__ xdbp, int nks,
                                                    const float* __restrict__ cw,
                                                    const float* __restrict__ cb,
                                                    const float* __restrict__ dpw,
                                                    const float* __restrict__ dpb,
                                                    const float* __restrict__ A_log,
                                                    const float* __restrict__ Dp,
                                                    const float* __restrict__ SB_S,
                                                    const float* __restrict__ SB_dt,
                                                    const float* __restrict__ BND){
  __shared__ float sRow[CHS*56];
  __shared__ float sU[CHS*256];
  int blk = blockIdx.x;
  int c = blk % NCH; int bd = blk / NCH; int dch = bd % 3; int b = bd / 3;
  int t = threadIdx.x; int d = dch*256 + t;
  int l0 = c*CHS;
  for (int i = t; i < CHS*56; i += 256){
    size_t base = ((size_t)(b*Ln + l0))*56 + i;
    float s = xdbp[base];
    for (int k = 1; k < nks; ++k) s += xdbp[(size_t)k*XDBS + base];
    sRow[i] = s;
  }
  float xv[CHS+3];
  #pragma unroll
  for (int j = 0; j < 3; ++j) xv[j] = BND[((size_t)blk*3 + j)*256 + t];
  const float* xp = xz + ((size_t)(b*Ln + l0))*1536 + d;
  #pragma unroll
  for (int i = 0; i < CHS; ++i) xv[3+i] = xp[(size_t)i*1536];
  float cw0 = cw[d*4+0], cw1 = cw[d*4+1], cw2 = cw[d*4+2], cw3 = cw[d*4+3];
  float cbv = cb[d];
  #pragma unroll
  for (int i = 0; i < CHS; ++i){
    float v = xv[i]*cw0 + xv[i+1]*cw1 + xv[i+2]*cw2 + xv[i+3]*cw3 + cbv;
    sU[i*256 + t] = v * fsig(v);
  }
  float w[DTR];
  const float* wp = dpw + (size_t)d*DTR;
  #pragma unroll
  for (int j = 0; j < DTR; ++j) w[j] = wp[j];
  float a2[DSt], h[DSt];
  const float* ap = A_log + (size_t)d*DSt;
  #pragma unroll
  for (int s = 0; s < DSt; ++s){ a2[s] = -__expf(ap[s]) * LOG2E; h[s] = 0.f; }
  for (int cc = 0; cc < c; ++cc){
    size_t base = (((size_t)bd*NCH + cc)*256 + t)*16;
    float sd = SB_dt[((size_t)bd*NCH + cc)*256 + t];
    #pragma unroll
    for (int s = 0; s < DSt; ++s)
      h[s] = exp2f(sd * a2[s]) * h[s] + SB_S[base + s];
  }
  float dbias = dpb[d];
  float Dd = Dp[d];
  float* ydst = xz + ((size_t)(b*Ln + l0))*1536 + dch*256;
  __syncthreads();
  for (int i = 0; i < CHS; ++i){
    int ro = i*56;
    float dtr = dbias;
    #pragma unroll
    for (int j = 0; j < DTR; ++j) dtr += w[j] * sRow[ro + j];
    float dtv = fsoftplus(dtr);
    float u = sU[i*256 + t];
    float du = dtv * u;
    float yv = 0.f;
    #pragma unroll
    for (int s = 0; s < DSt; ++s){
      h[s] = exp2f(dtv * a2[s]) * h[s] + du * sRow[ro + 24 + s];
      yv += h[s] * sRow[ro + 40 + s];
    }
    ydst[(size_t)i*1536 + t] = yv + u*Dd;
  }
}

// -------------------------------------------------- final two LayerNorms
__global__ __launch_bounds__(256) void final_ln_kernel(const float* __restrict__ h,
                                                       const float* __restrict__ res,
                                                       const float* w1, const float* b1,
                                                       const float* w2, const float* b2,
                                                       float* __restrict__ x){
  int wv = threadIdx.x >> 6, ln = threadIdx.x & 63;
  int tokid = blockIdx.x*4 + wv;
  const float* hr = h + (size_t)tokid*DM;
  const float* rr = res + (size_t)tokid*DM;
  float* xr = x + (size_t)tokid*DM;
  float v[6]; float s = 0.f;
  #pragma unroll
  for (int i = 0; i < 6; ++i){ int c = ln + 64*i; v[i] = hr[c] + rr[c]; s += v[i]; }
  #pragma unroll
  for (int o = 32; o > 0; o >>= 1) s += __shfl_xor(s, o);
  float mu = s * (1.f/DM); float q = 0.f;
  #pragma unroll
  for (int i = 0; i < 6; ++i){ float dd = v[i]-mu; q += dd*dd; }
  #pragma unroll
  for (int o = 32; o > 0; o >>= 1) q += __shfl_xor(q, o);
  float rstd = rsqrtf(q * (1.f/DM) + EPSf);
  float u[6]; float s2 = 0.f;
  #pragma unroll
  for (int i = 0; i < 6; ++i){ int c = ln + 64*i; u[i] = (v[i]-mu)*rstd*w1[c] + b1[c]; s2 += u[i]; }
  #pragma unroll
  for (int o = 32; o > 0; o >>= 1) s2 += __shfl_xor(s2, o);
  float mu2 = s2 * (1.f/DM); float q2 = 0.f;
  #pragma unroll
  for (int i = 0; i < 6; ++i){ float dd = u[i]-mu2; q2 += dd*dd; }
  #pragma unroll
  for (int o = 32; o > 0; o >>= 1) q2 += __shfl_xor(q2, o);
  float rstd2 = rsqrtf(q2 * (1.f/DM) + EPSf);
  #pragma unroll
  for (int i = 0; i < 6; ++i){ int c = ln + 64*i; xr[c] = (u[i]-mu2)*rstd2*w2[c] + b2[c]; }
}

// -------------------------------------------------- mean over L: stage 1 (partial sums, 8-way ILP)
__global__ __launch_bounds__(384) void mean_kernel(const float* __restrict__ x,
                                                   float* __restrict__ featp){
  int blk = blockIdx.x;
  int b = blk >> 2, g = blk & 3;
  int c = threadIdx.x;
  const float* xp = x + ((size_t)(b*Ln + g*96))*DM + c;
  float a0=0.f,a1=0.f,a2=0.f,a3=0.f,a4=0.f,a5=0.f,a6=0.f,a7=0.f;
  for (int l = 0; l < 96; l += 8){
    a0 += xp[(size_t)(l+0)*DM];
    a1 += xp[(size_t)(l+1)*DM];
    a2 += xp[(size_t)(l+2)*DM];
    a3 += xp[(size_t)(l+3)*DM];
    a4 += xp[(size_t)(l+4)*DM];
    a5 += xp[(size_t)(l+5)*DM];
    a6 += xp[(size_t)(l+6)*DM];
    a7 += xp[(size_t)(l+7)*DM];
  }
  featp[(size_t)blk*DM + c] = ((a0+a1)+(a2+a3)) + ((a4+a5)+(a6+a7));
}

// -------------------------------------------------- MLP head
__global__ __launch_bounds__(256) void head_mlp(const float* __restrict__ featp,
    const float* w1, const float* b1, const float* g1, const float* bb1,
    const float* w2, const float* b2, const float* g2, const float* bb2,
    const float* w3, const float* b3, float* __restrict__ out){
  int b = blockIdx.x; int t = threadIdx.x;
  __shared__ float f[DM]; __shared__ float h1[256]; __shared__ float h2[256];
  for (int i = t; i < DM; i += 256){
    f[i] = (featp[(size_t)(b*4+0)*DM + i] + featp[(size_t)(b*4+1)*DM + i]
          + featp[(size_t)(b*4+2)*DM + i] + featp[(size_t)(b*4+3)*DM + i]) * (1.f/Ln);
  }
  __syncthreads();
  {
    float a = b1[t];
    #pragma unroll 4
    for (int j = 0; j < DM; ++j) a += w1[(size_t)t*DM + j] * f[j];
    a = a * (g1[t] * BNS) + bb1[t];
    h1[t] = fmaxf(a, 0.f);
  }
  __syncthreads();
  {
    float a = b2[t];
    #pragma unroll 4
    for (int j = 0; j < 256; ++j) a += w2[(size_t)t*256 + j] * h1[j];
    a = a * (g2[t] * BNS) + bb2[t];
    h2[t] = fmaxf(a, 0.f);
  }
  __syncthreads();
  if (t < CLSn){
    float a = b3[t];
    for (int j = 0; j < 256; ++j) a += w3[(size_t)t*256 + j] * h2[j];
    out[b*CLSn + t] = a;
  }
}

extern "C" void kernel_launch(void* const* d_in, const int* in_sizes, int n_in,
                              void* d_out, int out_size, void* d_ws, size_t ws_size,
                              hipStream_t stream) {
  if (n_in < 42) return;
  if (out_size < Bn*CLSn) return;
  constexpr size_t WS_FLOATS = 3919936;
  if (ws_size < WS_FLOATS * sizeof(float)) return;
  constexpr size_t MIDF = 5812224;
  constexpr size_t BIGF = 9437184;       // R4-proven threshold (76.7 MB total)
  const bool mid = ws_size >= (WS_FLOATS + MIDF) * sizeof(float);
  const bool big = ws_size >= (WS_FLOATS + MIDF + BIGF) * sizeof(float);

  const float* pts       = (const float*)d_in[0];
  const float* enc_w1    = (const float*)d_in[1];  const float* enc_b1    = (const float*)d_in[2];
  const float* enc_bn1_g = (const float*)d_in[3];  const float* enc_bn1_b = (const float*)d_in[4];
  const float* enc_w2    = (const float*)d_in[5];  const float* enc_b2    = (const float*)d_in[6];
  const float* enc_w3    = (const float*)d_in[7];  const float* enc_b3    = (const float*)d_in[8];
  const float* enc_bn2_g = (const float*)d_in[9];  const float* enc_bn2_b = (const float*)d_in[10];
  const float* enc_w4    = (const float*)d_in[11]; const float* enc_b4    = (const float*)d_in[12];
  const float* pos_w1    = (const float*)d_in[13]; const float* pos_b1    = (const float*)d_in[14];
  const float* pos_w2    = (const float*)d_in[15]; const float* pos_b2    = (const float*)d_in[16];
  const float* ln_w      = (const float*)d_in[17]; const float* ln_b      = (const float*)d_in[18];
  const float* in_proj_w = (const float*)d_in[19];
  const float* conv_w    = (const float*)d_in[20]; const float* conv_b    = (const float*)d_in[21];
  const float* x_proj_w  = (const float*)d_in[22];
  const float* dt_proj_w = (const float*)d_in[23]; const float* dt_proj_b = (const float*)d_in[24];
  const float* A_log     = (const float*)d_in[25]; const float* D_param   = (const float*)d_in[26];
  const float* out_proj_w= (const float*)d_in[27];
  const float* normf_w   = (const float*)d_in[28]; const float* normf_b   = (const float*)d_in[29];
  const float* norm_w    = (const float*)d_in[30]; const float* norm_b    = (const float*)d_in[31];
  const float* head_w1   = (const float*)d_in[32]; const float* head_b1   = (const float*)d_in[33];
  const float* head_bn1_g= (const float*)d_in[34]; const float* head_bn1_b= (const float*)d_in[35];
  const float* head_w2   = (const float*)d_in[36]; const float* head_b2   = (const float*)d_in[37];
  const float* head_bn2_g= (const float*)d_in[38]; const float* head_bn2_b= (const float*)d_in[39];
  const float* head_w3   = (const float*)d_in[40]; const float* head_b3   = (const float*)d_in[41];

  float* ws = (float*)d_ws;
  float* hb   = ws;
  float* resb = ws + 589824;
  float* U    = ws + 1179648;
  // encoder phase (small path buffers in U)
  float* center = U;
  float* nb     = U + 1536;
  float* tok    = U + 50688;
  int*   order  = (int*)(U + 247296);
  bf16*  F3b_s  = (bf16*)(U + 262144);
  bf16*  F3c_s  = (bf16*)(U + 1310720);
  // layer phase (encoder buffers dead)
  float* xz   = U;
  float* xdb  = U + 2359296;
  bf16*  xb   = (bf16*)(U + 2445312);
  float* SBdt = U + 2445312;
  float* BND  = U + 2482176;
  float* SBS  = hb;
  float* xf   = U;
  float* featp = U + 589824;
  float* WB = ws + WS_FLOATS;
  bf16* wb_ip = (bf16*)WB;
  bf16* wb_op = (bf16*)(WB + 3538944);
  bf16* wb_xp = (bf16*)(WB + 5308416);
  bf16* wb_e2 = (bf16*)(WB + 5566464);
  bf16* wb_e3 = (bf16*)(WB + 5582848);
  bf16* wb_e4 = (bf16*)(WB + 5713920);
  // big region (floats beyond MIDF). Encoder: F3bB|F3cB (8.4M).
  // Layer phase (encoder dead): xdbp | xdbR | yb | SB_S | H0 | SB_dt = 6.57M < 9.4M.
  float* BIGB = WB + MIDF;
  bf16*  F3bB = (bf16*)BIGB;                    // 16384x512 bf16 (4,194,304 f)
  bf16*  F3cB = (bf16*)(BIGB + 4194304);        // 16384x512 bf16
  float* xdbp_b = BIGB;                         // 12*86016 = 1,032,192 f
  float* xdbR   = BIGB + 1032192;               // 86,016 f
  bf16*  yb     = (bf16*)(BIGB + 1118208);      // 1,179,648 bf16 (589,824 f)
  float* SBS_b  = BIGB + 1708032;               // 576*256*16 = 2,359,296 f
  float* H0b    = BIGB + 4067328;               // 2,359,296 f
  float* SBdt_b = BIGB + 6426624;               // 147,456 f -> ends 6,574,080

  // fps || (cvt_all when mid)
  front_kernel<<<mid ? (Bn + 11352) : Bn, 256, 0, stream>>>(pts, center,
      in_proj_w, out_proj_w, x_proj_w, enc_w2, enc_w3, enc_w4, (bf16*)WB);
  knn_kernel<<<Bn*Gn, 256, 0, stream>>>(pts, center, nb);

  if (big){
    enc2_kernel<bf16><<<dim3(256,2), 256, 0, stream>>>(nb, enc_w1, enc_b1,
        enc_bn1_g, enc_bn1_b, wb_e2, enc_b2, F3bB);
    gemm_mfma128<bf16,bf16,1,bf16,0><<<dim3(256,4), 256, 0, stream>>>(F3bB, 512,
        wb_e3, enc_b3, enc_bn2_g, enc_bn2_b, F3cB, 512, 16384, 512, 512);
    gemm_mfma128<bf16,bf16,0,float,2><<<dim3(256,3), 256, 0, stream>>>(F3cB, 512,
        wb_e4, enc_b4, nullptr, nullptr, (float*)tok, DM, 16384, 384, 512);
  } else {
    for (int b = 0; b < Bn; ++b){
      const float* nbc = nb + (size_t)b*MC*3;
      float* tokc = tok + (size_t)b*Gn*DM;
      if (mid){
        enc2_kernel<bf16><<<dim3(64,2), 256, 0, stream>>>(nbc, enc_w1, enc_b1,
            enc_bn1_g, enc_bn1_b, wb_e2, enc_b2, F3b_s);
        gemm_mfma128<bf16,bf16,1,bf16,0><<<dim3(64,4), 256, 0, stream>>>(F3b_s, 512,
            wb_e3, enc_b3, enc_bn2_g, enc_bn2_b, F3c_s, 512, MC, 512, 512);
        gemm_mfma128<bf16,bf16,0,float,2><<<dim3(64,3), 256, 0, stream>>>(F3c_s, 512,
            wb_e4, enc_b4, nullptr, nullptr, (float*)tokc, DM, MC, 384, 512);
      } else {
        enc2_kernel<float><<<dim3(64,2), 256, 0, stream>>>(nbc, enc_w1, enc_b1,
            enc_bn1_g, enc_bn1_b, enc_w2, enc_b2, F3b_s);
        gemm_mfma128<bf16,float,1,bf16,0><<<dim3(64,4), 256, 0, stream>>>(F3b_s, 512,
            enc_w3, enc_b3, enc_bn2_g, enc_bn2_b, F3c_s, 512, MC, 512, 512);
        gemm_mfma128<bf16,float,0,float,2><<<dim3(64,3), 256, 0, stream>>>(F3c_s, 512,
            enc_w4, enc_b4, nullptr, nullptr, (float*)tokc, DM, MC, 384, 512);
      }
    }
  }

  pos_sort_kernel<<<Bn*Gn + Bn*3, 128, 0, stream>>>(center, pos_w1, pos_b1,
      pos_w2, pos_b2, tok, order);

  const int nks = big ? 12 : 1;
  float* xdbp = big ? xdbp_b : xdb;

  for (int l = 0; l < DEPTH; ++l){
    const float* lnw  = ln_w      + (size_t)l*DM;
    const float* lnb  = ln_b      + (size_t)l*DM;
    const float* ipw  = in_proj_w + (size_t)l*1536*DM;
    const float* cw   = conv_w    + (size_t)l*DI*4;
    const float* cb   = conv_b    + (size_t)l*DI;
    const float* xpw  = x_proj_w  + (size_t)l*56*DI;
    const float* dpw  = dt_proj_w + (size_t)l*DI*DTR;
    const float* dpb  = dt_proj_b + (size_t)l*DI;
    const float* Alg  = A_log     + (size_t)l*DI*DSt;
    const float* Dpar = D_param   + (size_t)l*DI;
    const float* opw  = out_proj_w+ (size_t)l*DM*DI;

    if (l == 0)
      ln_res_first<<<Bn*Ln/4, 256, 0, stream>>>(tok, order, resb, xb, lnw, lnb);
    else
      ln_res_kernel<<<Bn*Ln/4, 256, 0, stream>>>(hb, resb, xb, lnw, lnb);
    if (mid){
      gemm_mfma128<bf16,bf16,0,float,0><<<dim3(24,12), 256, 0, stream>>>(xb, DM,
          wb_ip + (size_t)l*1536*DM, nullptr, nullptr, nullptr, xz, 1536, Bn*Ln, 1536, DM);
      xproj_kernel<bf16><<<dim3(24, nks), 256, 0, stream>>>(xz,
          wb_xp + (size_t)l*56*DI, cw, cb, xdbp, DI/nks);
    } else {
      gemm_mfma128<bf16,float,0,float,0><<<dim3(24,12), 256, 0, stream>>>(xb, DM, ipw,
          nullptr, nullptr, nullptr, xz, 1536, Bn*Ln, 1536, DM);
      xproj_kernel<float><<<dim3(24, nks), 256, 0, stream>>>(xz, xpw, cw, cb, xdbp, DI/nks);
    }
    if (big){
      scanA_big<<<Bn*3*NCB, 256, 0, stream>>>(xz, xdbp, nks, cw, cb,
          dpw, dpb, Alg, SBS_b, SBdt_b, xdbR);
      prefix_kernel<<<Bn*3*16, 256, 0, stream>>>(Alg, SBS_b, SBdt_b, H0b);
      scanB_big<<<Bn*3*NCB, 256, 0, stream>>>(xz, xdbR, cw, cb,
          dpw, dpb, Alg, Dpar, H0b, yb);
      gemm_mfma128<bf16,bf16,0,float,0><<<dim3(24,3), 256, 0, stream>>>(yb, DI,
          wb_op + (size_t)l*DM*DI, nullptr, nullptr, nullptr, hb, DM, Bn*Ln, 384, DI);
    } else {
      scanA_kernel<<<Bn*3*NCH, 256, 0, stream>>>(xz, xdbp, nks, cw, cb,
          dpw, dpb, Alg, SBS, SBdt, BND);
      scanB_kernel<<<Bn*3*NCH, 256, 0, stream>>>(xz, xdbp, nks, cw, cb,
          dpw, dpb, Alg, Dpar, SBS, SBdt, BND);
      if (mid){
        gemm_mfma64<float,bf16,0,1><<<dim3(24,6), 256, 0, stream>>>(xz, 1536,
            wb_op + (size_t)l*DM*DI, nullptr, xz, nullptr, hb, DM, Bn*Ln, DM, DI);
      } else {
        gemm_mfma64<float,float,0,1><<<dim3(24,6), 256, 0, stream>>>(xz, 1536, opw,
            nullptr, xz, nullptr, hb, DM, Bn*Ln, DM, DI);
      }
    }
  }

  final_ln_kernel<<<Bn*Ln/4, 256, 0, stream>>>(hb, resb, normf_w, normf_b, norm_w, norm_b, xf);
  mean_kernel<<<Bn*4, 384, 0, stream>>>(xf, featp);
  head_mlp<<<Bn, 256, 0, stream>>>(featp, head_w1, head_b1, head_bn1_g, head_bn1_b,
                                   head_w2, head_b2, head_bn2_g, head_bn2_b,
                                   head_w3, head_b3, (float*)d_out);
}